// Round 1
// baseline (489.256 us; speedup 1.0000x reference)
//
#include <hip/hip_runtime.h>

using short8 = __attribute__((ext_vector_type(8))) short;
using f32x4  = __attribute__((ext_vector_type(4))) float;

__device__ __forceinline__ unsigned short f2b(float f){
  unsigned int u = __float_as_uint(f);
  u = u + 0x7fffu + ((u >> 16) & 1u);   // round-to-nearest-even
  return (unsigned short)(u >> 16);
}
__device__ __forceinline__ float b2f(unsigned short s){
  return __uint_as_float(((unsigned int)s) << 16);
}

// ---------------- pooled = mean(w, axis=(2,3)) : [16,512] ----------------
__global__ __launch_bounds__(256) void k_pool(const float* __restrict__ w,
                                              float* __restrict__ pooled){
  int i = blockIdx.x * 256 + threadIdx.x;   // 8192
  const float* p = w + (size_t)i * 9;
  float s = 0.f;
  #pragma unroll
  for(int j = 0; j < 9; j++) s += p[j];
  pooled[i] = s * (1.f / 9.f);
}

// ------------- im2col of reflect-padded style map -> A_im bf16 [144][4608] -------------
// row = pos*16 + b (pos = oh*3+ow), k = cin*9 + kh*3 + kw
__global__ __launch_bounds__(256) void k_im2col(const float* __restrict__ w,
                                                unsigned short* __restrict__ A){
  int row = blockIdx.x;           // 144
  int pos = row >> 4, b = row & 15;
  int oh = pos / 3, ow = pos % 3;
  for(int k = threadIdx.x; k < 4608; k += 256){
    int cin = k / 9, q = k - cin * 9;
    int kh = q / 3, kw = q - kh * 3;
    int ih = oh + kh - 1, iw = ow + kw - 1;
    ih = ih < 0 ? -ih : (ih > 2 ? 4 - ih : ih);   // reflect for size-3
    iw = iw < 0 ? -iw : (iw > 2 ? 4 - iw : iw);
    float v = w[((size_t)(b * 512 + cin) * 3 + ih) * 3 + iw];
    A[(size_t)row * 4608 + k] = f2b(v);
  }
}

// ------------- pw[b][4096] and bias[b][512] (1x1 convs on pooled style) -------------
__global__ __launch_bounds__(256) void k_pwbias(const float* __restrict__ pooled,
    const float* __restrict__ kp_pw, const float* __restrict__ kp_pb,
    const float* __restrict__ kp_bw, const float* __restrict__ kp_bb,
    float* __restrict__ pw, float* __restrict__ bias){
  int wid = (blockIdx.x * 256 + threadIdx.x) >> 6;   // 4608 waves
  int lane = threadIdx.x & 63;
  const float* row;
  float bv;
  if(wid < 4096){ row = kp_pw + (size_t)wid * 512; bv = kp_pb[wid]; }
  else          { row = kp_bw + (size_t)(wid - 4096) * 512; bv = kp_bb[wid - 4096]; }
  float r[8];
  #pragma unroll
  for(int i = 0; i < 8; i++) r[i] = row[lane + 64 * i];
  for(int b = 0; b < 16; b++){
    float s = 0.f;
    #pragma unroll
    for(int i = 0; i < 8; i++) s += r[i] * pooled[b * 512 + lane + 64 * i];
    #pragma unroll
    for(int o = 32; o >= 1; o >>= 1) s += __shfl_xor(s, o, 64);
    if(lane == 0){
      if(wid < 4096) pw[b * 4096 + wid] = s + bv;
      else           bias[b * 512 + (wid - 4096)] = s + bv;
    }
  }
}

// ------------- KernelPredictor spatial GEMM: C[144,4096] = A[144,4608] x kp_sw^T -------------
// MFMA bf16, BM=144 (9 frag-rows), BN=64 (4 waves x 16 cols), BK=64. 64 blocks.
__global__ __launch_bounds__(256) void k_gemmB(const unsigned short* __restrict__ Aim,
    const float* __restrict__ kp_sw, const float* __restrict__ kp_sb,
    float* __restrict__ dw){
  __shared__ unsigned short Al[144 * 72];
  __shared__ unsigned short Bl[64 * 72];
  int tid = threadIdx.x;
  int lane = tid & 63, wv = tid >> 6;
  int n0 = blockIdx.x * 64;
  f32x4 acc[9] = {};
  for(int ks = 0; ks < 72; ks++){
    int kb = ks * 64;
    for(int c = tid; c < 1152; c += 256){
      int m = c >> 3, kc = c & 7;
      *(int4*)&Al[m * 72 + kc * 8] = *(const int4*)(Aim + (size_t)m * 4608 + kb + kc * 8);
    }
    for(int c = tid; c < 512; c += 256){
      int n = c >> 3, kc = c & 7;
      const float4* src = (const float4*)(kp_sw + (size_t)(n0 + n) * 4608 + kb + kc * 8);
      float4 v0 = src[0], v1 = src[1];
      unsigned short tmp[8];
      tmp[0]=f2b(v0.x); tmp[1]=f2b(v0.y); tmp[2]=f2b(v0.z); tmp[3]=f2b(v0.w);
      tmp[4]=f2b(v1.x); tmp[5]=f2b(v1.y); tmp[6]=f2b(v1.z); tmp[7]=f2b(v1.w);
      *(int4*)&Bl[n * 72 + kc * 8] = *(int4*)tmp;
    }
    __syncthreads();
    int r16 = lane & 15, khalf = lane >> 4;
    #pragma unroll
    for(int kk = 0; kk < 2; kk++){
      int ko = kk * 32 + khalf * 8;
      short8 bf = *(const short8*)&Bl[(wv * 16 + r16) * 72 + ko];
      #pragma unroll
      for(int mf = 0; mf < 9; mf++){
        short8 af = *(const short8*)&Al[(mf * 16 + r16) * 72 + ko];
        acc[mf] = __builtin_amdgcn_mfma_f32_16x16x32_bf16(af, bf, acc[mf], 0, 0, 0);
      }
    }
    __syncthreads();
  }
  int r16 = lane & 15, rgrp = lane >> 4;
  int n = n0 + wv * 16 + r16;
  float sb = kp_sb[n];
  #pragma unroll
  for(int mf = 0; mf < 9; mf++){
    #pragma unroll
    for(int r = 0; r < 4; r++){
      int b = rgrp * 4 + r;                       // row = mf*16 + rgrp*4 + r
      dw[((size_t)b * 4096 + n) * 9 + mf] = acc[mf][r] + sb;
    }
  }
}

// ---------------- instance-norm stats: mean, rstd per (b,c) ----------------
__global__ __launch_bounds__(256) void k_stats(const float* __restrict__ x,
                                               float* __restrict__ stats){
  int bc = blockIdx.x;                 // 8192
  const float* p = x + (size_t)bc * 1024;
  float s = 0.f, s2 = 0.f;
  for(int i = threadIdx.x; i < 1024; i += 256){ float v = p[i]; s += v; s2 += v * v; }
  int lane = threadIdx.x & 63, wv = threadIdx.x >> 6;
  #pragma unroll
  for(int o = 32; o >= 1; o >>= 1){ s += __shfl_xor(s, o, 64); s2 += __shfl_xor(s2, o, 64); }
  __shared__ float a4[4], b4[4];
  if(lane == 0){ a4[wv] = s; b4[wv] = s2; }
  __syncthreads();
  if(threadIdx.x == 0){
    float S = a4[0] + a4[1] + a4[2] + a4[3], S2 = b4[0] + b4[1] + b4[2] + b4[3];
    float m = S * (1.f / 1024.f);
    float var = S2 * (1.f / 1024.f) - m * m;
    stats[bc * 2]     = m;
    stats[bc * 2 + 1] = rsqrtf(var + 1e-5f);
  }
}

// ------ AdaConv fused: IN + reflect-pad + grouped spatial conv + grouped pointwise + bias ------
// block = (b, g); writes y0p NHWC padded bf16 [16][34][34][512] interior
__global__ __launch_bounds__(256) void k_ada(const float* __restrict__ x,
    const float* __restrict__ stats, const float* __restrict__ dwb,
    const float* __restrict__ pwb, const float* __restrict__ biasb,
    unsigned short* __restrict__ y0p){
  __shared__ float xn[8 * 1156];
  __shared__ float dwl[576];
  __shared__ float pwl[64];
  __shared__ float bl[8];
  int bg = blockIdx.x; int b = bg >> 6, g = bg & 63;
  int tid = threadIdx.x;
  for(int i = tid; i < 576; i += 256) dwl[i] = dwb[((size_t)b * 4096 + g * 64) * 9 + i];
  if(tid < 64) pwl[tid] = pwb[b * 4096 + g * 64 + tid];
  if(tid < 8)  bl[tid]  = biasb[b * 512 + g * 8 + tid];
  for(int idx = tid; idx < 8 * 1156; idx += 256){
    int ci = idx / 1156, p = idx - ci * 1156;
    int hh = p / 34, ww = p - hh * 34;
    int h = hh - 1, w2 = ww - 1;
    h  = h  < 0 ? -h  : (h  > 31 ? 62 - h  : h);
    w2 = w2 < 0 ? -w2 : (w2 > 31 ? 62 - w2 : w2);
    int c = b * 512 + g * 8 + ci;
    float m = stats[c * 2], rs = stats[c * 2 + 1];
    xn[idx] = (x[(size_t)c * 1024 + h * 32 + w2] - m) * rs;
  }
  __syncthreads();
  float acc[4][8] = {};
  #pragma unroll
  for(int i = 0; i < 8; i++){
    #pragma unroll
    for(int q = 0; q < 9; q++){
      int kh = q / 3, kw = q - kh * 3;
      float dvs[8];
      #pragma unroll
      for(int o = 0; o < 8; o++) dvs[o] = dwl[(o * 8 + i) * 9 + q];
      #pragma unroll
      for(int pp = 0; pp < 4; pp++){
        int p = pp * 256 + tid; int h = p >> 5, w = p & 31;
        float v = xn[i * 1156 + (h + kh) * 34 + (w + kw)];
        #pragma unroll
        for(int o = 0; o < 8; o++) acc[pp][o] += v * dvs[o];
      }
    }
  }
  #pragma unroll
  for(int pp = 0; pp < 4; pp++){
    int p = pp * 256 + tid; int h = p >> 5, w = p & 31;
    unsigned short pack[8];
    #pragma unroll
    for(int o = 0; o < 8; o++){
      float s = bl[o];
      #pragma unroll
      for(int i2 = 0; i2 < 8; i2++) s += pwl[o * 8 + i2] * acc[pp][i2];
      pack[o] = f2b(s);
    }
    *(int4*)&y0p[((size_t)(b * 34 + h + 1) * 34 + (w + 1)) * 512 + g * 8] = *(int4*)pack;
  }
}

// ------------- weight transform (Cout,Cin,3,3) fp32 -> [cout][q][cin] bf16 -------------
__global__ __launch_bounds__(256) void k_wt(const float* __restrict__ wsrc,
                                            unsigned short* __restrict__ wdst){
  __shared__ float ld[4608];
  int co = blockIdx.x;
  for(int i = threadIdx.x; i < 4608; i += 256) ld[i] = wsrc[(size_t)co * 4608 + i];
  __syncthreads();
  for(int i = threadIdx.x; i < 4608; i += 256){
    int q = i >> 9, cin = i & 511;
    wdst[(size_t)co * 4608 + i] = f2b(ld[cin * 9 + q]);
  }
}

// ------------- decoder 3x3 conv as implicit GEMM (bf16 MFMA), relu fused -------------
// input NHWC padded [16][34][34][512]; weights [cout][q][cin]; 128x128 tile, 4 waves
template<int NCOUT, int OUT_PADDED>
__global__ __launch_bounds__(256) void k_conv(const unsigned short* __restrict__ inp,
    const unsigned short* __restrict__ wt, const float* __restrict__ bias,
    unsigned short* __restrict__ outp){
  __shared__ unsigned short Al[128 * 72];
  __shared__ unsigned short Bl[128 * 72];
  int tid = threadIdx.x;
  int mt = blockIdx.x;                 // 128 m-tiles
  int n0 = blockIdx.y * 128;
  int b = mt >> 3, h0 = (mt & 7) * 4;
  int lane = tid & 63, wv = tid >> 6;
  int wm = (wv >> 1) * 64, wn = (wv & 1) * 64;
  f32x4 acc[4][4] = {};
  const size_t bbase = (size_t)b * 34 * 34 * 512;
  for(int q = 0; q < 9; q++){
    int kh = q / 3, kw = q - kh * 3;
    const unsigned short* wq = wt + (size_t)n0 * 4608 + q * 512;
    for(int cb = 0; cb < 8; cb++){
      int cin0 = cb * 64;
      #pragma unroll
      for(int j = 0; j < 4; j++){
        int c = tid + 256 * j;
        int m = c >> 3, kc = c & 7;
        int hh = h0 + (m >> 5) + kh, ww2 = (m & 31) + kw;
        *(int4*)&Al[m * 72 + kc * 8] =
          *(const int4*)(inp + bbase + ((size_t)(hh * 34 + ww2)) * 512 + cin0 + kc * 8);
      }
      #pragma unroll
      for(int j = 0; j < 4; j++){
        int c = tid + 256 * j;
        int n = c >> 3, kc = c & 7;
        *(int4*)&Bl[n * 72 + kc * 8] =
          *(const int4*)(wq + (size_t)n * 4608 + cin0 + kc * 8);
      }
      __syncthreads();
      int r16 = lane & 15, khalf = lane >> 4;
      #pragma unroll
      for(int kk = 0; kk < 2; kk++){
        int ko = kk * 32 + khalf * 8;
        short8 af[4], bf[4];
        #pragma unroll
        for(int i = 0; i < 4; i++) af[i] = *(const short8*)&Al[(wm + i * 16 + r16) * 72 + ko];
        #pragma unroll
        for(int i = 0; i < 4; i++) bf[i] = *(const short8*)&Bl[(wn + i * 16 + r16) * 72 + ko];
        #pragma unroll
        for(int mi = 0; mi < 4; mi++)
          #pragma unroll
          for(int ni = 0; ni < 4; ni++)
            acc[mi][ni] = __builtin_amdgcn_mfma_f32_16x16x32_bf16(af[mi], bf[ni], acc[mi][ni], 0, 0, 0);
      }
      __syncthreads();
    }
  }
  int r16 = lane & 15, rgrp = lane >> 4;
  #pragma unroll
  for(int ni = 0; ni < 4; ni++){
    int n = n0 + wn + ni * 16 + r16;
    float bv = bias[n];
    #pragma unroll
    for(int mi = 0; mi < 4; mi++){
      #pragma unroll
      for(int r = 0; r < 4; r++){
        int row = wm + mi * 16 + rgrp * 4 + r;
        int h = h0 + (row >> 5), w = row & 31;
        float v = acc[mi][ni][r] + bv;
        v = v > 0.f ? v : 0.f;
        size_t oidx;
        if(OUT_PADDED) oidx = ((size_t)(b * 34 + h + 1) * 34 + (w + 1)) * 512 + n;
        else           oidx = ((size_t)(b * 32 + h) * 32 + w) * NCOUT + n;
        outp[oidx] = f2b(v);
      }
    }
  }
}

// ------------- nearest 2x upsample + NHWC bf16 -> NCHW fp32 -------------
__global__ __launch_bounds__(256) void k_up(const unsigned short* __restrict__ y2,
                                            float* __restrict__ out){
  __shared__ unsigned short ld[32 * 258];
  int bh = blockIdx.x; int b = bh >> 5, h = bh & 31;
  int tid = threadIdx.x;
  const unsigned short* src = y2 + ((size_t)b * 1024 + h * 32) * 256;
  for(int c = tid; c < 1024; c += 256){
    int w = c >> 5, kc = c & 31;
    *(int4*)&ld[w * 258 + kc * 8] = *(const int4*)&src[w * 256 + kc * 8];
  }
  __syncthreads();
  int q = tid & 3, co0 = tid >> 2;
  for(int cc = 0; cc < 4; cc++){
    int co = cc * 64 + co0;
    size_t obase = ((size_t)(b * 256 + co) * 64 + h * 2) * 64 + q * 16;
    #pragma unroll
    for(int i = 0; i < 4; i++){
      float a  = b2f(ld[(q * 8 + i * 2) * 258 + co]);
      float b2 = b2f(ld[(q * 8 + i * 2 + 1) * 258 + co]);
      float4 v = make_float4(a, a, b2, b2);
      *(float4*)&out[obase + i * 4]      = v;
      *(float4*)&out[obase + 64 + i * 4] = v;
    }
  }
}

extern "C" void kernel_launch(void* const* d_in, const int* in_sizes, int n_in,
                              void* d_out, int out_size, void* d_ws, size_t ws_size,
                              hipStream_t stream){
  (void)in_sizes; (void)n_in; (void)out_size; (void)ws_size;
  const float* x      = (const float*)d_in[0];
  const float* w      = (const float*)d_in[1];
  const float* kp_sw  = (const float*)d_in[2];
  const float* kp_sb  = (const float*)d_in[3];
  const float* kp_pw  = (const float*)d_in[4];
  const float* kp_pb  = (const float*)d_in[5];
  const float* kp_bw  = (const float*)d_in[6];
  const float* kp_bb  = (const float*)d_in[7];
  const float* dec_w1 = (const float*)d_in[8];
  const float* dec_b1 = (const float*)d_in[9];
  const float* dec_w2 = (const float*)d_in[10];
  const float* dec_b2 = (const float*)d_in[11];
  char* ws = (char*)d_ws;
  float*          pooled = (float*)(ws);                        // 32 KB
  float*          pw     = (float*)(ws + 32768);                // 256 KB
  float*          bias   = (float*)(ws + 294912);               // 32 KB
  float*          stats  = (float*)(ws + 327680);               // 64 KB
  unsigned short* Aim    = (unsigned short*)(ws + 393216);      // 1.33 MB
  float*          dw     = (float*)(ws + 1720320);              // 2.36 MB
  unsigned short* w1t    = (unsigned short*)(ws + 4079616);     // 4.72 MB
  unsigned short* w2t    = (unsigned short*)(ws + 8798208);     // 2.36 MB
  unsigned short* y0p    = (unsigned short*)(ws + 11157504);    // 18.94 MB
  unsigned short* y1p    = (unsigned short*)(ws + 30097408);    // 18.94 MB
  unsigned short* y2     = (unsigned short*)(ws + 49037312);    // 8.39 MB

  hipMemsetAsync(y0p, 0, (size_t)16 * 34 * 34 * 512 * 2, stream);
  hipMemsetAsync(y1p, 0, (size_t)16 * 34 * 34 * 512 * 2, stream);
  k_pool  <<<32,   256, 0, stream>>>(w, pooled);
  k_im2col<<<144,  256, 0, stream>>>(w, Aim);
  k_pwbias<<<1152, 256, 0, stream>>>(pooled, kp_pw, kp_pb, kp_bw, kp_bb, pw, bias);
  k_gemmB <<<64,   256, 0, stream>>>(Aim, kp_sw, kp_sb, dw);
  k_stats <<<8192, 256, 0, stream>>>(x, stats);
  k_ada   <<<1024, 256, 0, stream>>>(x, stats, dw, pw, bias, y0p);
  k_wt    <<<512,  256, 0, stream>>>(dec_w1, w1t);
  k_wt    <<<256,  256, 0, stream>>>(dec_w2, w2t);
  k_conv<512, 1><<<dim3(128, 4), 256, 0, stream>>>(y0p, w1t, dec_b1, y1p);
  k_conv<256, 0><<<dim3(128, 2), 256, 0, stream>>>(y1p, w2t, dec_b2, y2);
  k_up    <<<512,  256, 0, stream>>>(y2, (float*)d_out);
}

// Round 2
// 352.221 us; speedup vs baseline: 1.3891x; 1.3891x over previous
//
#include <hip/hip_runtime.h>

using short8 = __attribute__((ext_vector_type(8))) short;
using f32x4  = __attribute__((ext_vector_type(4))) float;

__device__ __forceinline__ unsigned short f2b(float f){
  unsigned int u = __float_as_uint(f);
  u = u + 0x7fffu + ((u >> 16) & 1u);   // round-to-nearest-even
  return (unsigned short)(u >> 16);
}
__device__ __forceinline__ float b2f(unsigned short s){
  return __uint_as_float(((unsigned int)s) << 16);
}

// async global->LDS, 16B per lane; lds ptr must be wave-uniform base
__device__ __forceinline__ void gll16(const void* g, void* l){
  __builtin_amdgcn_global_load_lds(
      (const __attribute__((address_space(1))) unsigned int*)g,
      (__attribute__((address_space(3))) unsigned int*)l, 16, 0, 0);
}

// ---------------- pooled = mean(w, axis=(2,3)) : [16,512] ----------------
__global__ __launch_bounds__(256) void k_pool(const float* __restrict__ w,
                                              float* __restrict__ pooled){
  int i = blockIdx.x * 256 + threadIdx.x;   // 8192
  const float* p = w + (size_t)i * 9;
  float s = 0.f;
  #pragma unroll
  for(int j = 0; j < 9; j++) s += p[j];
  pooled[i] = s * (1.f / 9.f);
}

// ------------- im2col of reflect-padded style map -> A_im bf16 [144][4608] -------------
__global__ __launch_bounds__(256) void k_im2col(const float* __restrict__ w,
                                                unsigned short* __restrict__ A){
  int row = blockIdx.x;           // 144
  int pos = row >> 4, b = row & 15;
  int oh = pos / 3, ow = pos % 3;
  for(int k = threadIdx.x; k < 4608; k += 256){
    int cin = k / 9, q = k - cin * 9;
    int kh = q / 3, kw = q - kh * 3;
    int ih = oh + kh - 1, iw = ow + kw - 1;
    ih = ih < 0 ? -ih : (ih > 2 ? 4 - ih : ih);
    iw = iw < 0 ? -iw : (iw > 2 ? 4 - iw : iw);
    float v = w[((size_t)(b * 512 + cin) * 3 + ih) * 3 + iw];
    A[(size_t)row * 4608 + k] = f2b(v);
  }
}

// ------------- pw[b][4096] and bias[b][512] -------------
__global__ __launch_bounds__(256) void k_pwbias(const float* __restrict__ pooled,
    const float* __restrict__ kp_pw, const float* __restrict__ kp_pb,
    const float* __restrict__ kp_bw, const float* __restrict__ kp_bb,
    float* __restrict__ pw, float* __restrict__ bias){
  int wid = (blockIdx.x * 256 + threadIdx.x) >> 6;   // 4608 waves
  int lane = threadIdx.x & 63;
  const float* row;
  float bv;
  if(wid < 4096){ row = kp_pw + (size_t)wid * 512; bv = kp_pb[wid]; }
  else          { row = kp_bw + (size_t)(wid - 4096) * 512; bv = kp_bb[wid - 4096]; }
  float r[8];
  #pragma unroll
  for(int i = 0; i < 8; i++) r[i] = row[lane + 64 * i];
  for(int b = 0; b < 16; b++){
    float s = 0.f;
    #pragma unroll
    for(int i = 0; i < 8; i++) s += r[i] * pooled[b * 512 + lane + 64 * i];
    #pragma unroll
    for(int o = 32; o >= 1; o >>= 1) s += __shfl_xor(s, o, 64);
    if(lane == 0){
      if(wid < 4096) pw[b * 4096 + wid] = s + bv;
      else           bias[b * 512 + (wid - 4096)] = s + bv;
    }
  }
}

// ------------- KernelPredictor spatial GEMM, 8-way split-K -------------
// grid (64, 8): 64 n-tiles x 8 k-slices of 576. Partials fp32 [8][144][4096].
__global__ __launch_bounds__(256) void k_gemmB(const unsigned short* __restrict__ Aim,
    const float* __restrict__ kp_sw, float* __restrict__ part){
  __shared__ unsigned short Al[144 * 72];
  __shared__ unsigned short Bl[64 * 72];
  int tid = threadIdx.x;
  int lane = tid & 63, wv = tid >> 6;
  int n0 = blockIdx.x * 64;
  int kz = blockIdx.y;
  f32x4 acc[9] = {};
  for(int ks = kz * 9; ks < kz * 9 + 9; ks++){
    int kb = ks * 64;
    for(int c = tid; c < 1152; c += 256){
      int m = c >> 3, kc = c & 7;
      *(int4*)&Al[m * 72 + kc * 8] = *(const int4*)(Aim + (size_t)m * 4608 + kb + kc * 8);
    }
    for(int c = tid; c < 512; c += 256){
      int n = c >> 3, kc = c & 7;
      const float4* src = (const float4*)(kp_sw + (size_t)(n0 + n) * 4608 + kb + kc * 8);
      float4 v0 = src[0], v1 = src[1];
      unsigned short tmp[8];
      tmp[0]=f2b(v0.x); tmp[1]=f2b(v0.y); tmp[2]=f2b(v0.z); tmp[3]=f2b(v0.w);
      tmp[4]=f2b(v1.x); tmp[5]=f2b(v1.y); tmp[6]=f2b(v1.z); tmp[7]=f2b(v1.w);
      *(int4*)&Bl[n * 72 + kc * 8] = *(int4*)tmp;
    }
    __syncthreads();
    int r16 = lane & 15, khalf = lane >> 4;
    #pragma unroll
    for(int kk = 0; kk < 2; kk++){
      int ko = kk * 32 + khalf * 8;
      short8 bf = *(const short8*)&Bl[(wv * 16 + r16) * 72 + ko];
      #pragma unroll
      for(int mf = 0; mf < 9; mf++){
        short8 af = *(const short8*)&Al[(mf * 16 + r16) * 72 + ko];
        acc[mf] = __builtin_amdgcn_mfma_f32_16x16x32_bf16(af, bf, acc[mf], 0, 0, 0);
      }
    }
    __syncthreads();
  }
  int r16 = lane & 15, rgrp = lane >> 4;
  int n = n0 + wv * 16 + r16;
  #pragma unroll
  for(int mf = 0; mf < 9; mf++){
    #pragma unroll
    for(int r = 0; r < 4; r++){
      int m = mf * 16 + rgrp * 4 + r;
      part[((size_t)kz * 144 + m) * 4096 + n] = acc[mf][r];
    }
  }
}

// ------------- split-K reduce + bias + transpose into dw[b][n][9] -------------
__global__ __launch_bounds__(256) void k_red(const float* __restrict__ part,
    const float* __restrict__ kp_sb, float* __restrict__ dw){
  int i = blockIdx.x * 256 + threadIdx.x;   // 589824
  int m = i >> 12, n = i & 4095;
  float s = kp_sb[n];
  #pragma unroll
  for(int kz = 0; kz < 8; kz++) s += part[((size_t)kz * 144 + m) * 4096 + n];
  int q = m >> 4, b = m & 15;
  dw[((size_t)b * 4096 + n) * 9 + q] = s;
}

// ---------------- instance-norm stats ----------------
__global__ __launch_bounds__(256) void k_stats(const float* __restrict__ x,
                                               float* __restrict__ stats){
  int bc = blockIdx.x;                 // 8192
  const float* p = x + (size_t)bc * 1024;
  float s = 0.f, s2 = 0.f;
  for(int i = threadIdx.x; i < 1024; i += 256){ float v = p[i]; s += v; s2 += v * v; }
  int lane = threadIdx.x & 63, wv = threadIdx.x >> 6;
  #pragma unroll
  for(int o = 32; o >= 1; o >>= 1){ s += __shfl_xor(s, o, 64); s2 += __shfl_xor(s2, o, 64); }
  __shared__ float a4[4], b4[4];
  if(lane == 0){ a4[wv] = s; b4[wv] = s2; }
  __syncthreads();
  if(threadIdx.x == 0){
    float S = a4[0] + a4[1] + a4[2] + a4[3], S2 = b4[0] + b4[1] + b4[2] + b4[3];
    float m = S * (1.f / 1024.f);
    float var = S2 * (1.f / 1024.f) - m * m;
    stats[bc * 2]     = m;
    stats[bc * 2 + 1] = rsqrtf(var + 1e-5f);
  }
}

// ------ AdaConv fused ------
__global__ __launch_bounds__(256) void k_ada(const float* __restrict__ x,
    const float* __restrict__ stats, const float* __restrict__ dwb,
    const float* __restrict__ pwb, const float* __restrict__ biasb,
    unsigned short* __restrict__ y0p){
  __shared__ float xn[8 * 1156];
  __shared__ float dwl[576];
  __shared__ float pwl[64];
  __shared__ float bl[8];
  int bg = blockIdx.x; int b = bg >> 6, g = bg & 63;
  int tid = threadIdx.x;
  for(int i = tid; i < 576; i += 256) dwl[i] = dwb[((size_t)b * 4096 + g * 64) * 9 + i];
  if(tid < 64) pwl[tid] = pwb[b * 4096 + g * 64 + tid];
  if(tid < 8)  bl[tid]  = biasb[b * 512 + g * 8 + tid];
  for(int idx = tid; idx < 8 * 1156; idx += 256){
    int ci = idx / 1156, p = idx - ci * 1156;
    int hh = p / 34, ww = p - hh * 34;
    int h = hh - 1, w2 = ww - 1;
    h  = h  < 0 ? -h  : (h  > 31 ? 62 - h  : h);
    w2 = w2 < 0 ? -w2 : (w2 > 31 ? 62 - w2 : w2);
    int c = b * 512 + g * 8 + ci;
    float m = stats[c * 2], rs = stats[c * 2 + 1];
    xn[idx] = (x[(size_t)c * 1024 + h * 32 + w2] - m) * rs;
  }
  __syncthreads();
  float acc[4][8] = {};
  #pragma unroll
  for(int i = 0; i < 8; i++){
    #pragma unroll
    for(int q = 0; q < 9; q++){
      int kh = q / 3, kw = q - kh * 3;
      float dvs[8];
      #pragma unroll
      for(int o = 0; o < 8; o++) dvs[o] = dwl[(o * 8 + i) * 9 + q];
      #pragma unroll
      for(int pp = 0; pp < 4; pp++){
        int p = pp * 256 + tid; int h = p >> 5, w = p & 31;
        float v = xn[i * 1156 + (h + kh) * 34 + (w + kw)];
        #pragma unroll
        for(int o = 0; o < 8; o++) acc[pp][o] += v * dvs[o];
      }
    }
  }
  #pragma unroll
  for(int pp = 0; pp < 4; pp++){
    int p = pp * 256 + tid; int h = p >> 5, w = p & 31;
    unsigned short pack[8];
    #pragma unroll
    for(int o = 0; o < 8; o++){
      float s = bl[o];
      #pragma unroll
      for(int i2 = 0; i2 < 8; i2++) s += pwl[o * 8 + i2] * acc[pp][i2];
      pack[o] = f2b(s);
    }
    *(int4*)&y0p[((size_t)(b * 34 + h + 1) * 34 + (w + 1)) * 512 + g * 8] = *(int4*)pack;
  }
}

// ------------- weight transform (Cout,Cin,3,3) fp32 -> [cout][q][cin] bf16 -------------
__global__ __launch_bounds__(256) void k_wt(const float* __restrict__ wsrc,
                                            unsigned short* __restrict__ wdst){
  __shared__ float ld[4608];
  int co = blockIdx.x;
  for(int i = threadIdx.x; i < 4608; i += 256) ld[i] = wsrc[(size_t)co * 4608 + i];
  __syncthreads();
  for(int i = threadIdx.x; i < 4608; i += 256){
    int q = i >> 9, cin = i & 511;
    wdst[(size_t)co * 4608 + i] = f2b(ld[cin * 9 + q]);
  }
}

// ------------- decoder 3x3 conv: implicit GEMM, global_load_lds staging (m97 structure) -------------
// input NHWC padded [16][34][34][512]; weights [cout][q][cin]; 128x128 tile, 4 waves
// LDS linear stride-64 (no pad) so global_load_lds dest = wave-uniform base + lane*16
template<int NCOUT, int OUT_PADDED>
__global__ __launch_bounds__(256) void k_conv(const unsigned short* __restrict__ inp,
    const unsigned short* __restrict__ wt, const float* __restrict__ bias,
    unsigned short* __restrict__ outp){
  __shared__ unsigned short Al[128 * 64];
  __shared__ unsigned short Bl[128 * 64];
  int tid = threadIdx.x;
  int mt = blockIdx.x;                 // 128 m-tiles
  int n0 = blockIdx.y * 128;
  int b = mt >> 3, h0 = (mt & 7) * 4;
  int lane = tid & 63, wv = tid >> 6;
  int wm = (wv >> 1) * 64, wn = (wv & 1) * 64;
  f32x4 acc[4][4] = {};
  const size_t bbase = (size_t)b * 34 * 34 * 512;
  for(int q = 0; q < 9; q++){
    int kh = q / 3, kw = q - kh * 3;
    const unsigned short* wq = wt + (size_t)n0 * 4608 + q * 512;
    for(int cb = 0; cb < 8; cb++){
      int cin0 = cb * 64;
      #pragma unroll
      for(int j = 0; j < 4; j++){
        int c = tid + 256 * j;
        int m = c >> 3, kc = c & 7;
        int cbase = c & ~63;                      // wave-uniform
        int hh = h0 + (m >> 5) + kh, ww2 = (m & 31) + kw;
        gll16(inp + bbase + ((size_t)(hh * 34 + ww2)) * 512 + cin0 + kc * 8,
              &Al[cbase * 8]);
      }
      #pragma unroll
      for(int j = 0; j < 4; j++){
        int c = tid + 256 * j;
        int n = c >> 3, kc = c & 7;
        int cbase = c & ~63;
        gll16(wq + (size_t)n * 4608 + cin0 + kc * 8, &Bl[cbase * 8]);
      }
      __syncthreads();
      int r16 = lane & 15, khalf = lane >> 4;
      #pragma unroll
      for(int kk = 0; kk < 2; kk++){
        int ko = kk * 32 + khalf * 8;
        short8 af[4], bf[4];
        #pragma unroll
        for(int i = 0; i < 4; i++) af[i] = *(const short8*)&Al[(wm + i * 16 + r16) * 64 + ko];
        #pragma unroll
        for(int i = 0; i < 4; i++) bf[i] = *(const short8*)&Bl[(wn + i * 16 + r16) * 64 + ko];
        #pragma unroll
        for(int mi = 0; mi < 4; mi++)
          #pragma unroll
          for(int ni = 0; ni < 4; ni++)
            acc[mi][ni] = __builtin_amdgcn_mfma_f32_16x16x32_bf16(af[mi], bf[ni], acc[mi][ni], 0, 0, 0);
      }
      __syncthreads();
    }
  }
  int r16 = lane & 15, rgrp = lane >> 4;
  #pragma unroll
  for(int ni = 0; ni < 4; ni++){
    int n = n0 + wn + ni * 16 + r16;
    float bv = bias[n];
    #pragma unroll
    for(int mi = 0; mi < 4; mi++){
      #pragma unroll
      for(int r = 0; r < 4; r++){
        int row = wm + mi * 16 + rgrp * 4 + r;
        int h = h0 + (row >> 5), w = row & 31;
        float v = acc[mi][ni][r] + bv;
        v = v > 0.f ? v : 0.f;
        size_t oidx;
        if(OUT_PADDED) oidx = ((size_t)(b * 34 + h + 1) * 34 + (w + 1)) * 512 + n;
        else           oidx = ((size_t)(b * 32 + h) * 32 + w) * NCOUT + n;
        outp[oidx] = f2b(v);
      }
    }
  }
}

// ------------- nearest 2x upsample + NHWC bf16 -> NCHW fp32 -------------
__global__ __launch_bounds__(256) void k_up(const unsigned short* __restrict__ y2,
                                            float* __restrict__ out){
  __shared__ unsigned short ld[32 * 258];
  int bh = blockIdx.x; int b = bh >> 5, h = bh & 31;
  int tid = threadIdx.x;
  const unsigned short* src = y2 + ((size_t)b * 1024 + h * 32) * 256;
  for(int c = tid; c < 1024; c += 256){
    int w = c >> 5, kc = c & 31;
    *(int4*)&ld[w * 258 + kc * 8] = *(const int4*)&src[w * 256 + kc * 8];
  }
  __syncthreads();
  int q = tid & 3, co0 = tid >> 2;
  for(int cc = 0; cc < 4; cc++){
    int co = cc * 64 + co0;
    size_t obase = ((size_t)(b * 256 + co) * 64 + h * 2) * 64 + q * 16;
    #pragma unroll
    for(int i = 0; i < 4; i++){
      float a  = b2f(ld[(q * 8 + i * 2) * 258 + co]);
      float b2 = b2f(ld[(q * 8 + i * 2 + 1) * 258 + co]);
      float4 v = make_float4(a, a, b2, b2);
      *(float4*)&out[obase + i * 4]      = v;
      *(float4*)&out[obase + 64 + i * 4] = v;
    }
  }
}

extern "C" void kernel_launch(void* const* d_in, const int* in_sizes, int n_in,
                              void* d_out, int out_size, void* d_ws, size_t ws_size,
                              hipStream_t stream){
  (void)in_sizes; (void)n_in; (void)out_size; (void)ws_size;
  const float* x      = (const float*)d_in[0];
  const float* w      = (const float*)d_in[1];
  const float* kp_sw  = (const float*)d_in[2];
  const float* kp_sb  = (const float*)d_in[3];
  const float* kp_pw  = (const float*)d_in[4];
  const float* kp_pb  = (const float*)d_in[5];
  const float* kp_bw  = (const float*)d_in[6];
  const float* kp_bb  = (const float*)d_in[7];
  const float* dec_w1 = (const float*)d_in[8];
  const float* dec_b1 = (const float*)d_in[9];
  const float* dec_w2 = (const float*)d_in[10];
  const float* dec_b2 = (const float*)d_in[11];
  char* ws = (char*)d_ws;
  float*          pooled = (float*)(ws);                        // 32 KB
  float*          pw     = (float*)(ws + 32768);                // 256 KB
  float*          bias   = (float*)(ws + 294912);               // 32 KB
  float*          stats  = (float*)(ws + 327680);               // 64 KB
  unsigned short* Aim    = (unsigned short*)(ws + 393216);      // 1.33 MB
  float*          dw     = (float*)(ws + 1720320);              // 2.36 MB
  unsigned short* w1t    = (unsigned short*)(ws + 4079616);     // 4.72 MB
  unsigned short* w2t    = (unsigned short*)(ws + 8798208);     // 2.36 MB
  unsigned short* y0p    = (unsigned short*)(ws + 11157504);    // 18.94 MB
  unsigned short* y1p    = (unsigned short*)(ws + 30097408);    // 18.94 MB
  unsigned short* y2     = (unsigned short*)(ws + 49037312);    // 8.39 MB
  // split-K partials alias y1p (18.87 MB <= 18.94 MB); y1p memset happens AFTER k_red
  float*          part   = (float*)(ws + 30097408);

  hipMemsetAsync(y0p, 0, (size_t)16 * 34 * 34 * 512 * 2, stream);
  k_pool  <<<32,   256, 0, stream>>>(w, pooled);
  k_im2col<<<144,  256, 0, stream>>>(w, Aim);
  k_pwbias<<<1152, 256, 0, stream>>>(pooled, kp_pw, kp_pb, kp_bw, kp_bb, pw, bias);
  k_gemmB <<<dim3(64, 8), 256, 0, stream>>>(Aim, kp_sw, part);
  k_red   <<<2304, 256, 0, stream>>>(part, kp_sb, dw);
  hipMemsetAsync(y1p, 0, (size_t)16 * 34 * 34 * 512 * 2, stream);   // also clears part garbage
  k_stats <<<8192, 256, 0, stream>>>(x, stats);
  k_ada   <<<1024, 256, 0, stream>>>(x, stats, dw, pw, bias, y0p);
  k_wt    <<<512,  256, 0, stream>>>(dec_w1, w1t);
  k_wt    <<<256,  256, 0, stream>>>(dec_w2, w2t);
  k_conv<512, 1><<<dim3(128, 4), 256, 0, stream>>>(y0p, w1t, dec_b1, y1p);
  k_conv<256, 0><<<dim3(128, 2), 256, 0, stream>>>(y1p, w2t, dec_b2, y2);
  k_up    <<<512,  256, 0, stream>>>(y2, (float*)d_out);
}

// Round 3
// 285.071 us; speedup vs baseline: 1.7163x; 1.2356x over previous
//
#include <hip/hip_runtime.h>

using short8 = __attribute__((ext_vector_type(8))) short;
using f32x4  = __attribute__((ext_vector_type(4))) float;

__device__ __forceinline__ unsigned short f2b(float f){
  unsigned int u = __float_as_uint(f);
  u = u + 0x7fffu + ((u >> 16) & 1u);   // round-to-nearest-even
  return (unsigned short)(u >> 16);
}
__device__ __forceinline__ float b2f(unsigned short s){
  return __uint_as_float(((unsigned int)s) << 16);
}

// async global->LDS, 16B per lane; lds ptr must be wave-uniform base
__device__ __forceinline__ void gll16(const void* g, void* l){
  __builtin_amdgcn_global_load_lds(
      (const __attribute__((address_space(1))) unsigned int*)g,
      (__attribute__((address_space(3))) unsigned int*)l, 16, 0, 0);
}

// ---------------- pool (mean over 3x3) + im2col of reflect-padded style map ----------------
// blocks 0..143: im2col rows; blocks 144..175: pooled
__global__ __launch_bounds__(256) void k_prep(const float* __restrict__ w,
                                              unsigned short* __restrict__ A,
                                              float* __restrict__ pooled){
  if(blockIdx.x >= 144){
    int i = (blockIdx.x - 144) * 256 + threadIdx.x;   // 8192
    const float* p = w + (size_t)i * 9;
    float s = 0.f;
    #pragma unroll
    for(int j = 0; j < 9; j++) s += p[j];
    pooled[i] = s * (1.f / 9.f);
    return;
  }
  int row = blockIdx.x;           // 144
  int pos = row >> 4, b = row & 15;
  int oh = pos / 3, ow = pos % 3;
  for(int k = threadIdx.x; k < 4608; k += 256){
    int cin = k / 9, q = k - cin * 9;
    int kh = q / 3, kw = q - kh * 3;
    int ih = oh + kh - 1, iw = ow + kw - 1;
    ih = ih < 0 ? -ih : (ih > 2 ? 4 - ih : ih);
    iw = iw < 0 ? -iw : (iw > 2 ? 4 - iw : iw);
    float v = w[((size_t)(b * 512 + cin) * 3 + ih) * 3 + iw];
    A[(size_t)row * 4608 + k] = f2b(v);
  }
}

// ------------- pw[b][4096] and bias[b][512] -------------
__global__ __launch_bounds__(256) void k_pwbias(const float* __restrict__ pooled,
    const float* __restrict__ kp_pw, const float* __restrict__ kp_pb,
    const float* __restrict__ kp_bw, const float* __restrict__ kp_bb,
    float* __restrict__ pw, float* __restrict__ bias){
  int wid = (blockIdx.x * 256 + threadIdx.x) >> 6;   // 4608 waves
  int lane = threadIdx.x & 63;
  const float* row;
  float bv;
  if(wid < 4096){ row = kp_pw + (size_t)wid * 512; bv = kp_pb[wid]; }
  else          { row = kp_bw + (size_t)(wid - 4096) * 512; bv = kp_bb[wid - 4096]; }
  float r[8];
  #pragma unroll
  for(int i = 0; i < 8; i++) r[i] = row[lane + 64 * i];
  for(int b = 0; b < 16; b++){
    float s = 0.f;
    #pragma unroll
    for(int i = 0; i < 8; i++) s += r[i] * pooled[b * 512 + lane + 64 * i];
    #pragma unroll
    for(int o = 32; o >= 1; o >>= 1) s += __shfl_xor(s, o, 64);
    if(lane == 0){
      if(wid < 4096) pw[b * 4096 + wid] = s + bv;
      else           bias[b * 512 + (wid - 4096)] = s + bv;
    }
  }
}

// ------------- KernelPredictor spatial GEMM, 8-way split-K -------------
__global__ __launch_bounds__(256) void k_gemmB(const unsigned short* __restrict__ Aim,
    const float* __restrict__ kp_sw, float* __restrict__ part){
  __shared__ unsigned short Al[144 * 72];
  __shared__ unsigned short Bl[64 * 72];
  int tid = threadIdx.x;
  int lane = tid & 63, wv = tid >> 6;
  int n0 = blockIdx.x * 64;
  int kz = blockIdx.y;
  f32x4 acc[9] = {};
  for(int ks = kz * 9; ks < kz * 9 + 9; ks++){
    int kb = ks * 64;
    for(int c = tid; c < 1152; c += 256){
      int m = c >> 3, kc = c & 7;
      *(int4*)&Al[m * 72 + kc * 8] = *(const int4*)(Aim + (size_t)m * 4608 + kb + kc * 8);
    }
    for(int c = tid; c < 512; c += 256){
      int n = c >> 3, kc = c & 7;
      const float4* src = (const float4*)(kp_sw + (size_t)(n0 + n) * 4608 + kb + kc * 8);
      float4 v0 = src[0], v1 = src[1];
      unsigned short tmp[8];
      tmp[0]=f2b(v0.x); tmp[1]=f2b(v0.y); tmp[2]=f2b(v0.z); tmp[3]=f2b(v0.w);
      tmp[4]=f2b(v1.x); tmp[5]=f2b(v1.y); tmp[6]=f2b(v1.z); tmp[7]=f2b(v1.w);
      *(int4*)&Bl[n * 72 + kc * 8] = *(int4*)tmp;
    }
    __syncthreads();
    int r16 = lane & 15, khalf = lane >> 4;
    #pragma unroll
    for(int kk = 0; kk < 2; kk++){
      int ko = kk * 32 + khalf * 8;
      short8 bf = *(const short8*)&Bl[(wv * 16 + r16) * 72 + ko];
      #pragma unroll
      for(int mf = 0; mf < 9; mf++){
        short8 af = *(const short8*)&Al[(mf * 16 + r16) * 72 + ko];
        acc[mf] = __builtin_amdgcn_mfma_f32_16x16x32_bf16(af, bf, acc[mf], 0, 0, 0);
      }
    }
    __syncthreads();
  }
  int r16 = lane & 15, rgrp = lane >> 4;
  int n = n0 + wv * 16 + r16;
  #pragma unroll
  for(int mf = 0; mf < 9; mf++){
    #pragma unroll
    for(int r = 0; r < 4; r++){
      int m = mf * 16 + rgrp * 4 + r;
      part[((size_t)kz * 144 + m) * 4096 + n] = acc[mf][r];
    }
  }
}

// ------------- split-K reduce + bias + transpose into dw[b][n][9] -------------
__global__ __launch_bounds__(256) void k_red(const float* __restrict__ part,
    const float* __restrict__ kp_sb, float* __restrict__ dw){
  int i = blockIdx.x * 256 + threadIdx.x;   // 589824
  int m = i >> 12, n = i & 4095;
  float s = kp_sb[n];
  #pragma unroll
  for(int kz = 0; kz < 8; kz++) s += part[((size_t)kz * 144 + m) * 4096 + n];
  int q = m >> 4, b = m & 15;
  dw[((size_t)b * 4096 + n) * 9 + q] = s;
}

// ------ AdaConv fused: stats + IN + reflect-pad + grouped spatial + pointwise + bias + ring-zero ------
__global__ __launch_bounds__(256) void k_ada(const float* __restrict__ x,
    const float* __restrict__ dwb, const float* __restrict__ pwb,
    const float* __restrict__ biasb, unsigned short* __restrict__ y0p){
  __shared__ float xn[8][1156];
  __shared__ float dwl[576];
  __shared__ float pwl[64];
  __shared__ float bl[8];
  __shared__ float red0[4][8], red1[4][8];
  __shared__ float ms[8], rs[8];
  int bg = blockIdx.x; int b = bg >> 6, g = bg & 63;
  int tid = threadIdx.x;
  int lane = tid & 63, wv = tid >> 6;
  for(int i = tid; i < 576; i += 256) dwl[i] = dwb[((size_t)b * 4096 + g * 64) * 9 + i];
  if(tid < 64) pwl[tid] = pwb[b * 4096 + g * 64 + tid];
  if(tid < 8)  bl[tid]  = biasb[b * 512 + g * 8 + tid];
  // zero y0p pad ring for this (b,g) slice
  if(tid < 132){
    int e = tid, hh, ww;
    if(e < 34){ hh = 0; ww = e; }
    else if(e < 68){ hh = 33; ww = e - 34; }
    else if(e < 100){ hh = e - 68 + 1; ww = 0; }
    else { hh = e - 100 + 1; ww = 33; }
    int4 z = {0, 0, 0, 0};
    *(int4*)&y0p[((size_t)(b * 34 + hh) * 34 + ww) * 512 + g * 8] = z;
  }
  // load interior + per-channel partial sums
  const float* xb = x + ((size_t)(b * 512 + g * 8)) * 1024;
  float s[8], s2[8];
  #pragma unroll
  for(int ci = 0; ci < 8; ci++){
    s[ci] = 0.f; s2[ci] = 0.f;
    #pragma unroll
    for(int r = 0; r < 4; r++){
      int p = r * 256 + tid;
      float v = xb[ci * 1024 + p];
      xn[ci][((p >> 5) + 1) * 34 + (p & 31) + 1] = v;
      s[ci] += v; s2[ci] += v * v;
    }
  }
  #pragma unroll
  for(int ci = 0; ci < 8; ci++){
    #pragma unroll
    for(int o = 32; o >= 1; o >>= 1){
      s[ci]  += __shfl_xor(s[ci],  o, 64);
      s2[ci] += __shfl_xor(s2[ci], o, 64);
    }
  }
  if(lane == 0){
    #pragma unroll
    for(int ci = 0; ci < 8; ci++){ red0[wv][ci] = s[ci]; red1[wv][ci] = s2[ci]; }
  }
  __syncthreads();
  if(tid < 8){
    float S  = red0[0][tid] + red0[1][tid] + red0[2][tid] + red0[3][tid];
    float S2 = red1[0][tid] + red1[1][tid] + red1[2][tid] + red1[3][tid];
    float m = S * (1.f / 1024.f);
    ms[tid] = m;
    rs[tid] = rsqrtf(S2 * (1.f / 1024.f) - m * m + 1e-5f);
  }
  __syncthreads();
  // normalize interior in place
  #pragma unroll
  for(int ci = 0; ci < 8; ci++){
    float m = ms[ci], r = rs[ci];
    #pragma unroll
    for(int rr = 0; rr < 4; rr++){
      int p = rr * 256 + tid;
      int idx = ((p >> 5) + 1) * 34 + (p & 31) + 1;
      xn[ci][idx] = (xn[ci][idx] - m) * r;
    }
  }
  __syncthreads();
  // fill reflect halo from normalized interior
  for(int idx = tid; idx < 1056; idx += 256){
    int ci = idx / 132, e = idx - ci * 132;
    int hh, ww;
    if(e < 34){ hh = 0; ww = e; }
    else if(e < 68){ hh = 33; ww = e - 34; }
    else if(e < 100){ hh = e - 68 + 1; ww = 0; }
    else { hh = e - 100 + 1; ww = 33; }
    int h = hh - 1, w2 = ww - 1;
    h  = h  < 0 ? 1 : (h  > 31 ? 30 : h);
    w2 = w2 < 0 ? 1 : (w2 > 31 ? 30 : w2);
    xn[ci][hh * 34 + ww] = xn[ci][(h + 1) * 34 + (w2 + 1)];
  }
  __syncthreads();
  // grouped spatial conv + pointwise + bias
  float acc[4][8] = {};
  #pragma unroll
  for(int i = 0; i < 8; i++){
    #pragma unroll
    for(int q = 0; q < 9; q++){
      int kh = q / 3, kw = q - kh * 3;
      float dvs[8];
      #pragma unroll
      for(int o = 0; o < 8; o++) dvs[o] = dwl[(o * 8 + i) * 9 + q];
      #pragma unroll
      for(int pp = 0; pp < 4; pp++){
        int p = pp * 256 + tid; int h = p >> 5, w = p & 31;
        float v = xn[i][(h + kh) * 34 + (w + kw)];
        #pragma unroll
        for(int o = 0; o < 8; o++) acc[pp][o] += v * dvs[o];
      }
    }
  }
  #pragma unroll
  for(int pp = 0; pp < 4; pp++){
    int p = pp * 256 + tid; int h = p >> 5, w = p & 31;
    unsigned short pack[8];
    #pragma unroll
    for(int o = 0; o < 8; o++){
      float sv = bl[o];
      #pragma unroll
      for(int i2 = 0; i2 < 8; i2++) sv += pwl[o * 8 + i2] * acc[pp][i2];
      pack[o] = f2b(sv);
    }
    *(int4*)&y0p[((size_t)(b * 34 + h + 1) * 34 + (w + 1)) * 512 + g * 8] = *(int4*)pack;
  }
}

// ------------- weight transform both decoder convs: fp32 (Cout,Cin,3,3) -> bf16 [cout][q][cin] -------------
__global__ __launch_bounds__(256) void k_wt(const float* __restrict__ w1,
    const float* __restrict__ w2, unsigned short* __restrict__ d1,
    unsigned short* __restrict__ d2){
  __shared__ float ld[4608];
  int co = blockIdx.x;    // 768
  const float* src = (co < 512) ? (w1 + (size_t)co * 4608) : (w2 + (size_t)(co - 512) * 4608);
  unsigned short* dst = (co < 512) ? (d1 + (size_t)co * 4608) : (d2 + (size_t)(co - 512) * 4608);
  for(int i = threadIdx.x; i < 4608; i += 256) ld[i] = src[i];
  __syncthreads();
  for(int i = threadIdx.x; i < 4608; i += 256){
    int q = i >> 9, cin = i & 511;
    dst[i] = f2b(ld[cin * 9 + q]);
  }
}

// ------------- decoder 3x3 conv: implicit GEMM, dbuf + swizzled LDS + single barrier -------------
// 512 threads = 8 waves (2M x 4N), per-wave 64x32 out. LDS [2][128][64] bf16 per operand.
// T2 swizzle: LDS slot (row, col) holds data col ^ (row&7); gload_lds dest linear,
// source pre-swizzled, ds_read swizzled (involution, rule 21).
template<int NCOUT, int OUT_PADDED>
__global__ __launch_bounds__(512, 4) void k_conv(const unsigned short* __restrict__ inp,
    const unsigned short* __restrict__ wt, const float* __restrict__ bias,
    unsigned short* __restrict__ outp){
  __shared__ unsigned short Al[2][128 * 64];
  __shared__ unsigned short Bl[2][128 * 64];
  int tid = threadIdx.x;
  int mt = blockIdx.x;                 // 128 m-tiles
  int n0 = blockIdx.y * 128;
  int b = mt >> 3, h0 = (mt & 7) * 4;
  int lane = tid & 63, wv = tid >> 6;
  int wm = (wv >> 2) * 64, wn = (wv & 3) * 32;
  f32x4 acc[4][2] = {};
  const size_t bbase = (size_t)b * 34 * 34 * 512;

  // staging constants (per thread): chunks c = tid + 512*j, row = c>>3, slot = c&7
  int kc = tid & 7;
  int m0 = tid >> 3, m1 = (tid + 512) >> 3;
  int colA0 = kc ^ (m0 & 7), colA1 = kc ^ (m1 & 7);
  int mh0 = m0 >> 5, mw0 = m0 & 31;
  int mh1 = m1 >> 5, mw1 = m1 & 31;
  int ldsO0 = (tid & ~63) * 8;
  int ldsO1 = ldsO0 + 512 * 8;
  const unsigned short* a0base = inp + bbase + colA0 * 8;
  const unsigned short* a1base = inp + bbase + colA1 * 8;
  const unsigned short* b0base = wt + (size_t)(n0 + m0) * 4608 + colA0 * 8;
  const unsigned short* b1base = wt + (size_t)(n0 + m1) * 4608 + colA1 * 8;

  // prologue: stage t=0 (q=0: kh=0,kw=0; cb=0)
  gll16(a0base + (size_t)((h0 + mh0) * 34 + mw0) * 512, &Al[0][ldsO0]);
  gll16(a1base + (size_t)((h0 + mh1) * 34 + mw1) * 512, &Al[0][ldsO1]);
  gll16(b0base, &Bl[0][ldsO0]);
  gll16(b1base, &Bl[0][ldsO1]);
  __syncthreads();

  int r16 = lane & 15, khalf = lane >> 4;
  int cur = 0;
  for(int t = 0; t < 72; t++){
    int tn = t + 1;
    int nq = tn >> 3, ncb = tn & 7;
    int nkh = nq / 3, nkw = nq - nkh * 3;
    // issue A-stage for t+1
    if(tn < 72){
      gll16(a0base + (size_t)((h0 + mh0 + nkh) * 34 + mw0 + nkw) * 512 + ncb * 64,
            &Al[cur ^ 1][ldsO0]);
      gll16(a1base + (size_t)((h0 + mh1 + nkh) * 34 + mw1 + nkw) * 512 + ncb * 64,
            &Al[cur ^ 1][ldsO1]);
    }
    // compute kk=0
    {
      int sc8 = (khalf ^ (r16 & 7)) * 8;
      short8 af[4], bf[2];
      #pragma unroll
      for(int i = 0; i < 4; i++) af[i] = *(const short8*)&Al[cur][(wm + i * 16 + r16) * 64 + sc8];
      #pragma unroll
      for(int i = 0; i < 2; i++) bf[i] = *(const short8*)&Bl[cur][(wn + i * 16 + r16) * 64 + sc8];
      __builtin_amdgcn_s_setprio(1);
      #pragma unroll
      for(int mi = 0; mi < 4; mi++)
        #pragma unroll
        for(int ni = 0; ni < 2; ni++)
          acc[mi][ni] = __builtin_amdgcn_mfma_f32_16x16x32_bf16(af[mi], bf[ni], acc[mi][ni], 0, 0, 0);
      __builtin_amdgcn_s_setprio(0);
    }
    // issue B-stage for t+1
    if(tn < 72){
      gll16(b0base + (size_t)nq * 512 + ncb * 64, &Bl[cur ^ 1][ldsO0]);
      gll16(b1base + (size_t)nq * 512 + ncb * 64, &Bl[cur ^ 1][ldsO1]);
    }
    // compute kk=1
    {
      int sc8 = ((4 + khalf) ^ (r16 & 7)) * 8;
      short8 af[4], bf[2];
      #pragma unroll
      for(int i = 0; i < 4; i++) af[i] = *(const short8*)&Al[cur][(wm + i * 16 + r16) * 64 + sc8];
      #pragma unroll
      for(int i = 0; i < 2; i++) bf[i] = *(const short8*)&Bl[cur][(wn + i * 16 + r16) * 64 + sc8];
      __builtin_amdgcn_s_setprio(1);
      #pragma unroll
      for(int mi = 0; mi < 4; mi++)
        #pragma unroll
        for(int ni = 0; ni < 2; ni++)
          acc[mi][ni] = __builtin_amdgcn_mfma_f32_16x16x32_bf16(af[mi], bf[ni], acc[mi][ni], 0, 0, 0);
      __builtin_amdgcn_s_setprio(0);
    }
    __syncthreads();   // drains vmcnt: next buffer ready; cur buffer free to overwrite
    cur ^= 1;
  }

  int rgrp = lane >> 4;
  #pragma unroll
  for(int ni = 0; ni < 2; ni++){
    int n = n0 + wn + ni * 16 + r16;
    float bv = bias[n];
    #pragma unroll
    for(int mi = 0; mi < 4; mi++){
      #pragma unroll
      for(int r = 0; r < 4; r++){
        int row = wm + mi * 16 + rgrp * 4 + r;
        int h = h0 + (row >> 5), w = row & 31;
        float v = acc[mi][ni][r] + bv;
        v = v > 0.f ? v : 0.f;
        size_t oidx;
        if(OUT_PADDED) oidx = ((size_t)(b * 34 + h + 1) * 34 + (w + 1)) * 512 + n;
        else           oidx = ((size_t)(b * 32 + h) * 32 + w) * NCOUT + n;
        outp[oidx] = f2b(v);
      }
    }
  }
}

// ------------- nearest 2x upsample + NHWC bf16 -> NCHW fp32 -------------
__global__ __launch_bounds__(256) void k_up(const unsigned short* __restrict__ y2,
                                            float* __restrict__ out){
  __shared__ unsigned short ld[32 * 258];
  int bh = blockIdx.x; int b = bh >> 5, h = bh & 31;
  int tid = threadIdx.x;
  const unsigned short* src = y2 + ((size_t)b * 1024 + h * 32) * 256;
  for(int c = tid; c < 1024; c += 256){
    int w = c >> 5, kc = c & 31;
    *(int4*)&ld[w * 258 + kc * 8] = *(const int4*)&src[w * 256 + kc * 8];
  }
  __syncthreads();
  int q = tid & 3, co0 = tid >> 2;
  for(int cc = 0; cc < 4; cc++){
    int co = cc * 64 + co0;
    size_t obase = ((size_t)(b * 256 + co) * 64 + h * 2) * 64 + q * 16;
    #pragma unroll
    for(int i = 0; i < 4; i++){
      float a  = b2f(ld[(q * 8 + i * 2) * 258 + co]);
      float b2 = b2f(ld[(q * 8 + i * 2 + 1) * 258 + co]);
      float4 v = make_float4(a, a, b2, b2);
      *(float4*)&out[obase + i * 4]      = v;
      *(float4*)&out[obase + 64 + i * 4] = v;
    }
  }
}

extern "C" void kernel_launch(void* const* d_in, const int* in_sizes, int n_in,
                              void* d_out, int out_size, void* d_ws, size_t ws_size,
                              hipStream_t stream){
  (void)in_sizes; (void)n_in; (void)out_size; (void)ws_size;
  const float* x      = (const float*)d_in[0];
  const float* w      = (const float*)d_in[1];
  const float* kp_sw  = (const float*)d_in[2];
  const float* kp_sb  = (const float*)d_in[3];
  const float* kp_pw  = (const float*)d_in[4];
  const float* kp_pb  = (const float*)d_in[5];
  const float* kp_bw  = (const float*)d_in[6];
  const float* kp_bb  = (const float*)d_in[7];
  const float* dec_w1 = (const float*)d_in[8];
  const float* dec_b1 = (const float*)d_in[9];
  const float* dec_w2 = (const float*)d_in[10];
  const float* dec_b2 = (const float*)d_in[11];
  char* ws = (char*)d_ws;
  float*          pooled = (float*)(ws);                        // 32 KB
  float*          pw     = (float*)(ws + 32768);                // 256 KB
  float*          bias   = (float*)(ws + 294912);               // 32 KB
  unsigned short* Aim    = (unsigned short*)(ws + 393216);      // 1.33 MB
  float*          dw     = (float*)(ws + 1720320);              // 2.36 MB
  unsigned short* w1t    = (unsigned short*)(ws + 4079616);     // 4.72 MB
  unsigned short* w2t    = (unsigned short*)(ws + 8798208);     // 2.36 MB
  unsigned short* y0p    = (unsigned short*)(ws + 11157504);    // 18.94 MB
  unsigned short* y1p    = (unsigned short*)(ws + 30097408);    // 18.94 MB
  unsigned short* y2     = (unsigned short*)(ws + 49037312);    // 8.39 MB
  // split-K partials alias y1p; y1p memset happens AFTER k_red
  float*          part   = (float*)(ws + 30097408);

  k_prep  <<<176,  256, 0, stream>>>(w, Aim, pooled);
  k_pwbias<<<1152, 256, 0, stream>>>(pooled, kp_pw, kp_pb, kp_bw, kp_bb, pw, bias);
  k_gemmB <<<dim3(64, 8), 256, 0, stream>>>(Aim, kp_sw, part);
  k_red   <<<2304, 256, 0, stream>>>(part, kp_sb, dw);
  hipMemsetAsync(y1p, 0, (size_t)16 * 34 * 34 * 512 * 2, stream);   // clears part garbage + pad ring
  k_ada   <<<1024, 256, 0, stream>>>(x, dw, pw, bias, y0p);
  k_wt    <<<768,  256, 0, stream>>>(dec_w1, dec_w2, w1t, w2t);
  k_conv<512, 1><<<dim3(128, 4), 512, 0, stream>>>(y0p, w1t, dec_b1, y1p);
  k_conv<256, 0><<<dim3(128, 2), 512, 0, stream>>>(y1p, w2t, dec_b2, y2);
  k_up    <<<512,  256, 0, stream>>>(y2, (float*)d_out);
}

// Round 4
// 257.393 us; speedup vs baseline: 1.9008x; 1.1075x over previous
//
#include <hip/hip_runtime.h>

using short8 = __attribute__((ext_vector_type(8))) short;
using f32x4  = __attribute__((ext_vector_type(4))) float;

__device__ __forceinline__ unsigned short f2b(float f){
  unsigned int u = __float_as_uint(f);
  u = u + 0x7fffu + ((u >> 16) & 1u);   // round-to-nearest-even
  return (unsigned short)(u >> 16);
}
__device__ __forceinline__ float b2f(unsigned short s){
  return __uint_as_float(((unsigned int)s) << 16);
}

// async global->LDS, 16B per lane; lds ptr must be wave-uniform base
__device__ __forceinline__ void gll16(const void* g, void* l){
  __builtin_amdgcn_global_load_lds(
      (const __attribute__((address_space(1))) unsigned int*)g,
      (__attribute__((address_space(3))) unsigned int*)l, 16, 0, 0);
}
__device__ __forceinline__ void vm_wait8(){ asm volatile("s_waitcnt vmcnt(8)" ::: "memory"); }
__device__ __forceinline__ void vm_wait4(){ asm volatile("s_waitcnt vmcnt(4)" ::: "memory"); }
__device__ __forceinline__ void vm_wait0(){ asm volatile("s_waitcnt vmcnt(0)" ::: "memory"); }

// ------- fused: im2col (0..143) + pool (144..175) + decoder weight transform (176..943) -------
__global__ __launch_bounds__(256) void k_prepwt(const float* __restrict__ w,
    unsigned short* __restrict__ A, float* __restrict__ pooled,
    const float* __restrict__ w1, const float* __restrict__ w2,
    unsigned short* __restrict__ d1, unsigned short* __restrict__ d2){
  int bid = blockIdx.x;
  if(bid >= 176){
    __shared__ float ld[4608];
    int co = bid - 176;    // 768
    const float* src = (co < 512) ? (w1 + (size_t)co * 4608) : (w2 + (size_t)(co - 512) * 4608);
    unsigned short* dst = (co < 512) ? (d1 + (size_t)co * 4608) : (d2 + (size_t)(co - 512) * 4608);
    for(int i = threadIdx.x; i < 4608; i += 256) ld[i] = src[i];
    __syncthreads();
    for(int i = threadIdx.x; i < 4608; i += 256){
      int q = i >> 9, cin = i & 511;
      dst[i] = f2b(ld[cin * 9 + q]);
    }
    return;
  }
  if(bid >= 144){
    int i = (bid - 144) * 256 + threadIdx.x;   // 8192
    const float* p = w + (size_t)i * 9;
    float s = 0.f;
    #pragma unroll
    for(int j = 0; j < 9; j++) s += p[j];
    pooled[i] = s * (1.f / 9.f);
    return;
  }
  int row = bid;           // 144
  int pos = row >> 4, b = row & 15;
  int oh = pos / 3, ow = pos % 3;
  for(int k = threadIdx.x; k < 4608; k += 256){
    int cin = k / 9, q = k - cin * 9;
    int kh = q / 3, kw = q - kh * 3;
    int ih = oh + kh - 1, iw = ow + kw - 1;
    ih = ih < 0 ? -ih : (ih > 2 ? 4 - ih : ih);
    iw = iw < 0 ? -iw : (iw > 2 ? 4 - iw : iw);
    float v = w[((size_t)(b * 512 + cin) * 3 + ih) * 3 + iw];
    A[(size_t)row * 4608 + k] = f2b(v);
  }
}

// ------------- pw[b][4096] and bias[b][512] -------------
__global__ __launch_bounds__(256) void k_pwbias(const float* __restrict__ pooled,
    const float* __restrict__ kp_pw, const float* __restrict__ kp_pb,
    const float* __restrict__ kp_bw, const float* __restrict__ kp_bb,
    float* __restrict__ pw, float* __restrict__ bias){
  int wid = (blockIdx.x * 256 + threadIdx.x) >> 6;   // 4608 waves
  int lane = threadIdx.x & 63;
  const float* row;
  float bv;
  if(wid < 4096){ row = kp_pw + (size_t)wid * 512; bv = kp_pb[wid]; }
  else          { row = kp_bw + (size_t)(wid - 4096) * 512; bv = kp_bb[wid - 4096]; }
  float r[8];
  #pragma unroll
  for(int i = 0; i < 8; i++) r[i] = row[lane + 64 * i];
  for(int b = 0; b < 16; b++){
    float s = 0.f;
    #pragma unroll
    for(int i = 0; i < 8; i++) s += r[i] * pooled[b * 512 + lane + 64 * i];
    #pragma unroll
    for(int o = 32; o >= 1; o >>= 1) s += __shfl_xor(s, o, 64);
    if(lane == 0){
      if(wid < 4096) pw[b * 4096 + wid] = s + bv;
      else           bias[b * 512 + (wid - 4096)] = s + bv;
    }
  }
}

// ------------- KernelPredictor spatial GEMM, 12-way split-K -------------
__global__ __launch_bounds__(256) void k_gemmB(const unsigned short* __restrict__ Aim,
    const float* __restrict__ kp_sw, float* __restrict__ part){
  __shared__ unsigned short Al[144 * 72];
  __shared__ unsigned short Bl[64 * 72];
  int tid = threadIdx.x;
  int lane = tid & 63, wv = tid >> 6;
  int n0 = blockIdx.x * 64;
  int kz = blockIdx.y;
  f32x4 acc[9] = {};
  for(int ks = kz * 6; ks < kz * 6 + 6; ks++){
    int kb = ks * 64;
    for(int c = tid; c < 1152; c += 256){
      int m = c >> 3, kc = c & 7;
      *(int4*)&Al[m * 72 + kc * 8] = *(const int4*)(Aim + (size_t)m * 4608 + kb + kc * 8);
    }
    for(int c = tid; c < 512; c += 256){
      int n = c >> 3, kc = c & 7;
      const float4* src = (const float4*)(kp_sw + (size_t)(n0 + n) * 4608 + kb + kc * 8);
      float4 v0 = src[0], v1 = src[1];
      unsigned short tmp[8];
      tmp[0]=f2b(v0.x); tmp[1]=f2b(v0.y); tmp[2]=f2b(v0.z); tmp[3]=f2b(v0.w);
      tmp[4]=f2b(v1.x); tmp[5]=f2b(v1.y); tmp[6]=f2b(v1.z); tmp[7]=f2b(v1.w);
      *(int4*)&Bl[n * 72 + kc * 8] = *(int4*)tmp;
    }
    __syncthreads();
    int r16 = lane & 15, khalf = lane >> 4;
    #pragma unroll
    for(int kk = 0; kk < 2; kk++){
      int ko = kk * 32 + khalf * 8;
      short8 bf = *(const short8*)&Bl[(wv * 16 + r16) * 72 + ko];
      #pragma unroll
      for(int mf = 0; mf < 9; mf++){
        short8 af = *(const short8*)&Al[(mf * 16 + r16) * 72 + ko];
        acc[mf] = __builtin_amdgcn_mfma_f32_16x16x32_bf16(af, bf, acc[mf], 0, 0, 0);
      }
    }
    __syncthreads();
  }
  int r16 = lane & 15, rgrp = lane >> 4;
  int n = n0 + wv * 16 + r16;
  #pragma unroll
  for(int mf = 0; mf < 9; mf++){
    #pragma unroll
    for(int r = 0; r < 4; r++){
      int m = mf * 16 + rgrp * 4 + r;
      part[((size_t)kz * 144 + m) * 4096 + n] = acc[mf][r];
    }
  }
}

// ------------- split-K reduce + bias + transpose into dw[b][n][9] -------------
__global__ __launch_bounds__(256) void k_red(const float* __restrict__ part,
    const float* __restrict__ kp_sb, float* __restrict__ dw){
  int i = blockIdx.x * 256 + threadIdx.x;   // 589824
  int m = i >> 12, n = i & 4095;
  float s = kp_sb[n];
  #pragma unroll
  for(int kz = 0; kz < 12; kz++) s += part[((size_t)kz * 144 + m) * 4096 + n];
  int q = m >> 4, b = m & 15;
  dw[((size_t)b * 4096 + n) * 9 + q] = s;
}

// ------------- zero the pad ring of y1p (interior is fully written by conv1) -------------
__global__ __launch_bounds__(256) void k_ring(unsigned short* __restrict__ y1p){
  int i = blockIdx.x * 256 + threadIdx.x;   // 528*256 = 135168 = 16*132*64
  int b = i / 8448, rem = i - b * 8448;
  int e = rem >> 6, ch8 = rem & 63;
  int hh, ww;
  if(e < 34){ hh = 0; ww = e; }
  else if(e < 68){ hh = 33; ww = e - 34; }
  else if(e < 100){ hh = e - 68 + 1; ww = 0; }
  else { hh = e - 100 + 1; ww = 33; }
  int4 z = {0, 0, 0, 0};
  *(int4*)&y1p[((size_t)(b * 34 + hh) * 34 + ww) * 512 + ch8 * 8] = z;
}

// ------ AdaConv fused: stats + IN + reflect-pad + grouped spatial + pointwise + bias + ring-zero ------
__global__ __launch_bounds__(256) void k_ada(const float* __restrict__ x,
    const float* __restrict__ dwb, const float* __restrict__ pwb,
    const float* __restrict__ biasb, unsigned short* __restrict__ y0p){
  __shared__ float xn[8][1156];
  __shared__ float dwl[576];
  __shared__ float pwl[64];
  __shared__ float bl[8];
  __shared__ float red0[4][8], red1[4][8];
  __shared__ float ms[8], rs[8];
  int bg = blockIdx.x; int b = bg >> 6, g = bg & 63;
  int tid = threadIdx.x;
  int lane = tid & 63, wv = tid >> 6;
  for(int i = tid; i < 576; i += 256) dwl[i] = dwb[((size_t)b * 4096 + g * 64) * 9 + i];
  if(tid < 64) pwl[tid] = pwb[b * 4096 + g * 64 + tid];
  if(tid < 8)  bl[tid]  = biasb[b * 512 + g * 8 + tid];
  // zero y0p pad ring for this (b,g) slice
  if(tid < 132){
    int e = tid, hh, ww;
    if(e < 34){ hh = 0; ww = e; }
    else if(e < 68){ hh = 33; ww = e - 34; }
    else if(e < 100){ hh = e - 68 + 1; ww = 0; }
    else { hh = e - 100 + 1; ww = 33; }
    int4 z = {0, 0, 0, 0};
    *(int4*)&y0p[((size_t)(b * 34 + hh) * 34 + ww) * 512 + g * 8] = z;
  }
  // load interior (float4) + per-channel partial sums
  const float* xb = x + ((size_t)(b * 512 + g * 8)) * 1024;
  int h4 = tid >> 3, w4 = (tid & 7) * 4;
  float s[8], s2[8];
  #pragma unroll
  for(int ci = 0; ci < 8; ci++){
    float4 v = *(const float4*)(xb + ci * 1024 + tid * 4);
    float* dst = &xn[ci][(h4 + 1) * 34 + w4 + 1];
    dst[0] = v.x; dst[1] = v.y; dst[2] = v.z; dst[3] = v.w;
    s[ci]  = v.x + v.y + v.z + v.w;
    s2[ci] = v.x * v.x + v.y * v.y + v.z * v.z + v.w * v.w;
  }
  #pragma unroll
  for(int ci = 0; ci < 8; ci++){
    #pragma unroll
    for(int o = 32; o >= 1; o >>= 1){
      s[ci]  += __shfl_xor(s[ci],  o, 64);
      s2[ci] += __shfl_xor(s2[ci], o, 64);
    }
  }
  if(lane == 0){
    #pragma unroll
    for(int ci = 0; ci < 8; ci++){ red0[wv][ci] = s[ci]; red1[wv][ci] = s2[ci]; }
  }
  __syncthreads();
  if(tid < 8){
    float S  = red0[0][tid] + red0[1][tid] + red0[2][tid] + red0[3][tid];
    float S2 = red1[0][tid] + red1[1][tid] + red1[2][tid] + red1[3][tid];
    float m = S * (1.f / 1024.f);
    ms[tid] = m;
    rs[tid] = rsqrtf(S2 * (1.f / 1024.f) - m * m + 1e-5f);
  }
  __syncthreads();
  // normalize interior in place
  #pragma unroll
  for(int ci = 0; ci < 8; ci++){
    float m = ms[ci], r = rs[ci];
    float* p = &xn[ci][(h4 + 1) * 34 + w4 + 1];
    #pragma unroll
    for(int j = 0; j < 4; j++) p[j] = (p[j] - m) * r;
  }
  __syncthreads();
  // fill reflect halo from normalized interior
  for(int idx = tid; idx < 1056; idx += 256){
    int ci = idx / 132, e = idx - ci * 132;
    int hh, ww;
    if(e < 34){ hh = 0; ww = e; }
    else if(e < 68){ hh = 33; ww = e - 34; }
    else if(e < 100){ hh = e - 68 + 1; ww = 0; }
    else { hh = e - 100 + 1; ww = 33; }
    int h = hh - 1, w2 = ww - 1;
    h  = h  < 0 ? 1 : (h  > 31 ? 30 : h);
    w2 = w2 < 0 ? 1 : (w2 > 31 ? 30 : w2);
    xn[ci][hh * 34 + ww] = xn[ci][(h + 1) * 34 + (w2 + 1)];
  }
  __syncthreads();
  // grouped spatial conv + pointwise + bias
  float acc[4][8] = {};
  #pragma unroll
  for(int i = 0; i < 8; i++){
    #pragma unroll
    for(int q = 0; q < 9; q++){
      int kh = q / 3, kw = q - kh * 3;
      float dvs[8];
      #pragma unroll
      for(int o = 0; o < 8; o++) dvs[o] = dwl[(o * 8 + i) * 9 + q];
      #pragma unroll
      for(int pp = 0; pp < 4; pp++){
        int p = pp * 256 + tid; int h = p >> 5, w = p & 31;
        float v = xn[i][(h + kh) * 34 + (w + kw)];
        #pragma unroll
        for(int o = 0; o < 8; o++) acc[pp][o] += v * dvs[o];
      }
    }
  }
  #pragma unroll
  for(int pp = 0; pp < 4; pp++){
    int p = pp * 256 + tid; int h = p >> 5, w = p & 31;
    unsigned short pack[8];
    #pragma unroll
    for(int o = 0; o < 8; o++){
      float sv = bl[o];
      #pragma unroll
      for(int i2 = 0; i2 < 8; i2++) sv += pwl[o * 8 + i2] * acc[pp][i2];
      pack[o] = f2b(sv);
    }
    *(int4*)&y0p[((size_t)(b * 34 + h + 1) * 34 + (w + 1)) * 512 + g * 8] = *(int4*)pack;
  }
}

// ------------- decoder 3x3 conv: implicit GEMM, 4-buffer distance-2 counted-vmcnt pipeline -------------
// 512 threads = 8 waves (2M x 4N), per-wave 64x32 out. LDS 4 x ([128][64] A + [128][64] B) = 128 KB.
// T2 swizzle via pre-swizzled global source + swizzled ds_read (involution col ^= row&7).
// One s_barrier per K-step, s_waitcnt vmcnt(8) counted (never 0 in main loop) — T4.
template<int NCOUT, int OUT_PADDED>
__global__ __launch_bounds__(512) void k_conv(const unsigned short* __restrict__ inp,
    const unsigned short* __restrict__ wt, const float* __restrict__ bias,
    unsigned short* __restrict__ outp){
  __shared__ unsigned short Al[4][128 * 64];
  __shared__ unsigned short Bl[4][128 * 64];
  int tid = threadIdx.x;
  int mt = blockIdx.x;                 // 128 m-tiles
  int n0 = blockIdx.y * 128;
  int b = mt >> 3, h0 = (mt & 7) * 4;
  int lane = tid & 63, wv = tid >> 6;
  int wm = (wv >> 2) * 64, wn = (wv & 3) * 32;
  f32x4 acc[4][2] = {};
  const size_t bbase = (size_t)b * 34 * 34 * 512;

  // staging constants: chunks c = tid + 512*j, row = c>>3, slot = c&7
  int kc = tid & 7;
  int m0 = tid >> 3, m1 = (tid + 512) >> 3;
  int colA0 = kc ^ (m0 & 7), colA1 = kc ^ (m1 & 7);
  int mh0 = m0 >> 5, mw0 = m0 & 31;
  int mh1 = m1 >> 5, mw1 = m1 & 31;
  int ldsO0 = (tid & ~63) * 8;
  int ldsO1 = ldsO0 + 512 * 8;
  const unsigned short* a0base = inp + bbase + colA0 * 8;
  const unsigned short* a1base = inp + bbase + colA1 * 8;
  const unsigned short* b0base = wt + (size_t)(n0 + m0) * 4608 + colA0 * 8;
  const unsigned short* b1base = wt + (size_t)(n0 + m1) * 4608 + colA1 * 8;
  int r16 = lane & 15, khalf = lane >> 4;

#define STAGE(T, BUF) { \
    int q_ = (T) >> 3, cb_ = ((T) & 7) * 64; \
    int kh_ = q_ / 3, kw_ = q_ - kh_ * 3; \
    gll16(a0base + (size_t)((h0 + mh0 + kh_) * 34 + mw0 + kw_) * 512 + cb_, &Al[BUF][ldsO0]); \
    gll16(a1base + (size_t)((h0 + mh1 + kh_) * 34 + mw1 + kw_) * 512 + cb_, &Al[BUF][ldsO1]); \
    gll16(b0base + (size_t)q_ * 512 + cb_, &Bl[BUF][ldsO0]); \
    gll16(b1base + (size_t)q_ * 512 + cb_, &Bl[BUF][ldsO1]); }

#define COMPUTE(BUF) { \
    const unsigned short* Ab = Al[BUF]; const unsigned short* Bb = Bl[BUF]; \
    { int sc8 = (khalf ^ (r16 & 7)) * 8; \
      short8 af[4], bf[2]; \
      _Pragma("unroll") for(int i = 0; i < 4; i++) af[i] = *(const short8*)&Ab[(wm + i * 16 + r16) * 64 + sc8]; \
      _Pragma("unroll") for(int i = 0; i < 2; i++) bf[i] = *(const short8*)&Bb[(wn + i * 16 + r16) * 64 + sc8]; \
      __builtin_amdgcn_s_setprio(1); \
      _Pragma("unroll") for(int mi = 0; mi < 4; mi++) \
        _Pragma("unroll") for(int ni = 0; ni < 2; ni++) \
          acc[mi][ni] = __builtin_amdgcn_mfma_f32_16x16x32_bf16(af[mi], bf[ni], acc[mi][ni], 0, 0, 0); \
      __builtin_amdgcn_s_setprio(0); } \
    { int sc8 = ((4 + khalf) ^ (r16 & 7)) * 8; \
      short8 af[4], bf[2]; \
      _Pragma("unroll") for(int i = 0; i < 4; i++) af[i] = *(const short8*)&Ab[(wm + i * 16 + r16) * 64 + sc8]; \
      _Pragma("unroll") for(int i = 0; i < 2; i++) bf[i] = *(const short8*)&Bb[(wn + i * 16 + r16) * 64 + sc8]; \
      __builtin_amdgcn_s_setprio(1); \
      _Pragma("unroll") for(int mi = 0; mi < 4; mi++) \
        _Pragma("unroll") for(int ni = 0; ni < 2; ni++) \
          acc[mi][ni] = __builtin_amdgcn_mfma_f32_16x16x32_bf16(af[mi], bf[ni], acc[mi][ni], 0, 0, 0); \
      __builtin_amdgcn_s_setprio(0); } }

  // prologue: buffers 0,1 in flight
  STAGE(0, 0)
  STAGE(1, 1)
  // main loop: 68 steps, fully static buffer indices
  for(int t = 0; t < 68; t += 4){
    STAGE(t + 2, 2) vm_wait8(); __builtin_amdgcn_s_barrier(); COMPUTE(0)
    STAGE(t + 3, 3) vm_wait8(); __builtin_amdgcn_s_barrier(); COMPUTE(1)
    STAGE(t + 4, 0) vm_wait8(); __builtin_amdgcn_s_barrier(); COMPUTE(2)
    STAGE(t + 5, 1) vm_wait8(); __builtin_amdgcn_s_barrier(); COMPUTE(3)
  }
  // peel t = 68..71
  STAGE(70, 2) vm_wait8(); __builtin_amdgcn_s_barrier(); COMPUTE(0)
  STAGE(71, 3) vm_wait8(); __builtin_amdgcn_s_barrier(); COMPUTE(1)
  vm_wait4(); __builtin_amdgcn_s_barrier(); COMPUTE(2)
  vm_wait0(); __builtin_amdgcn_s_barrier(); COMPUTE(3)
#undef STAGE
#undef COMPUTE

  int rgrp = lane >> 4;
  #pragma unroll
  for(int ni = 0; ni < 2; ni++){
    int n = n0 + wn + ni * 16 + r16;
    float bv = bias[n];
    #pragma unroll
    for(int mi = 0; mi < 4; mi++){
      #pragma unroll
      for(int r = 0; r < 4; r++){
        int row = wm + mi * 16 + rgrp * 4 + r;
        int h = h0 + (row >> 5), w = row & 31;
        float v = acc[mi][ni][r] + bv;
        v = v > 0.f ? v : 0.f;
        size_t oidx;
        if(OUT_PADDED) oidx = ((size_t)(b * 34 + h + 1) * 34 + (w + 1)) * 512 + n;
        else           oidx = ((size_t)(b * 32 + h) * 32 + w) * NCOUT + n;
        outp[oidx] = f2b(v);
      }
    }
  }
}

// ------------- nearest 2x upsample + NHWC bf16 -> NCHW fp32 -------------
__global__ __launch_bounds__(256) void k_up(const unsigned short* __restrict__ y2,
                                            float* __restrict__ out){
  __shared__ unsigned short ld[32 * 258];
  int bh = blockIdx.x; int b = bh >> 5, h = bh & 31;
  int tid = threadIdx.x;
  const unsigned short* src = y2 + ((size_t)b * 1024 + h * 32) * 256;
  for(int c = tid; c < 1024; c += 256){
    int w = c >> 5, kc = c & 31;
    *(int4*)&ld[w * 258 + kc * 8] = *(const int4*)&src[w * 256 + kc * 8];
  }
  __syncthreads();
  int q = tid & 3, co0 = tid >> 2;
  for(int cc = 0; cc < 4; cc++){
    int co = cc * 64 + co0;
    size_t obase = ((size_t)(b * 256 + co) * 64 + h * 2) * 64 + q * 16;
    #pragma unroll
    for(int i = 0; i < 4; i++){
      float a  = b2f(ld[(q * 8 + i * 2) * 258 + co]);
      float b2 = b2f(ld[(q * 8 + i * 2 + 1) * 258 + co]);
      float4 v = make_float4(a, a, b2, b2);
      *(float4*)&out[obase + i * 4]      = v;
      *(float4*)&out[obase + 64 + i * 4] = v;
    }
  }
}

extern "C" void kernel_launch(void* const* d_in, const int* in_sizes, int n_in,
                              void* d_out, int out_size, void* d_ws, size_t ws_size,
                              hipStream_t stream){
  (void)in_sizes; (void)n_in; (void)out_size; (void)ws_size;
  const float* x      = (const float*)d_in[0];
  const float* w      = (const float*)d_in[1];
  const float* kp_sw  = (const float*)d_in[2];
  const float* kp_sb  = (const float*)d_in[3];
  const float* kp_pw  = (const float*)d_in[4];
  const float* kp_pb  = (const float*)d_in[5];
  const float* kp_bw  = (const float*)d_in[6];
  const float* kp_bb  = (const float*)d_in[7];
  const float* dec_w1 = (const float*)d_in[8];
  const float* dec_b1 = (const float*)d_in[9];
  const float* dec_w2 = (const float*)d_in[10];
  const float* dec_b2 = (const float*)d_in[11];
  char* ws = (char*)d_ws;
  float*          pooled = (float*)(ws);                        // 32 KB
  float*          pw     = (float*)(ws + 32768);                // 256 KB
  float*          bias   = (float*)(ws + 294912);               // 32 KB
  unsigned short* Aim    = (unsigned short*)(ws + 393216);      // 1.33 MB
  float*          dw     = (float*)(ws + 1720320);              // 2.36 MB
  unsigned short* w1t    = (unsigned short*)(ws + 4079616);     // 4.72 MB
  unsigned short* w2t    = (unsigned short*)(ws + 8798208);     // 2.36 MB
  unsigned short* y0p    = (unsigned short*)(ws + 11157504);    // 18.94 MB
  unsigned short* y1p    = (unsigned short*)(ws + 30097408);    // 18.94 MB
  unsigned short* y2     = (unsigned short*)(ws + 49037312);    // 8.39 MB
  // split-K partials (12 x 144 x 4096 fp32 = 28.3 MB) alias y0p+y1p head;
  // consumed by k_red BEFORE k_ada/k_ring/k_conv overwrite that region.
  float*          part   = (float*)(ws + 11157504);

  k_prepwt<<<944,  256, 0, stream>>>(w, Aim, pooled, dec_w1, dec_w2, w1t, w2t);
  k_pwbias<<<1152, 256, 0, stream>>>(pooled, kp_pw, kp_pb, kp_bw, kp_bb, pw, bias);
  k_gemmB <<<dim3(64, 12), 256, 0, stream>>>(Aim, kp_sw, part);
  k_red   <<<2304, 256, 0, stream>>>(part, kp_sb, dw);
  k_ring  <<<528,  256, 0, stream>>>(y1p);
  k_ada   <<<1024, 256, 0, stream>>>(x, dw, pw, bias, y0p);
  k_conv<512, 1><<<dim3(128, 4), 512, 0, stream>>>(y0p, w1t, dec_b1, y1p);
  k_conv<256, 0><<<dim3(128, 2), 512, 0, stream>>>(y1p, w2t, dec_b2, y2);
  k_up    <<<512,  256, 0, stream>>>(y2, (float*)d_out);
}

// Round 5
// 250.667 us; speedup vs baseline: 1.9518x; 1.0268x over previous
//
#include <hip/hip_runtime.h>

using short8 = __attribute__((ext_vector_type(8))) short;
using f32x4  = __attribute__((ext_vector_type(4))) float;

__device__ __forceinline__ unsigned short f2b(float f){
  unsigned int u = __float_as_uint(f);
  u = u + 0x7fffu + ((u >> 16) & 1u);   // round-to-nearest-even
  return (unsigned short)(u >> 16);
}
__device__ __forceinline__ float b2f(unsigned short s){
  return __uint_as_float(((unsigned int)s) << 16);
}

// async global->LDS, 16B per lane; lds ptr must be wave-uniform base
__device__ __forceinline__ void gll16(const void* g, void* l){
  __builtin_amdgcn_global_load_lds(
      (const __attribute__((address_space(1))) unsigned int*)g,
      (__attribute__((address_space(3))) unsigned int*)l, 16, 0, 0);
}
__device__ __forceinline__ void vm_wait4(){ asm volatile("s_waitcnt vmcnt(4)" ::: "memory"); }
__device__ __forceinline__ void vm_wait0(){ asm volatile("s_waitcnt vmcnt(0)" ::: "memory"); }

// ------- fused: im2col (0..143) + pool (144..175) + decoder weight transform (176..943) -------
__global__ __launch_bounds__(256) void k_prepwt(const float* __restrict__ w,
    unsigned short* __restrict__ A, float* __restrict__ pooled,
    const float* __restrict__ w1, const float* __restrict__ w2,
    unsigned short* __restrict__ d1, unsigned short* __restrict__ d2){
  int bid = blockIdx.x;
  if(bid >= 176){
    __shared__ float ld[4608];
    int co = bid - 176;    // 768
    const float* src = (co < 512) ? (w1 + (size_t)co * 4608) : (w2 + (size_t)(co - 512) * 4608);
    unsigned short* dst = (co < 512) ? (d1 + (size_t)co * 4608) : (d2 + (size_t)(co - 512) * 4608);
    for(int i = threadIdx.x; i < 4608; i += 256) ld[i] = src[i];
    __syncthreads();
    for(int i = threadIdx.x; i < 4608; i += 256){
      int q = i >> 9, cin = i & 511;
      dst[i] = f2b(ld[cin * 9 + q]);
    }
    return;
  }
  if(bid >= 144){
    int i = (bid - 144) * 256 + threadIdx.x;   // 8192
    const float* p = w + (size_t)i * 9;
    float s = 0.f;
    #pragma unroll
    for(int j = 0; j < 9; j++) s += p[j];
    pooled[i] = s * (1.f / 9.f);
    return;
  }
  int row = bid;           // 144
  int pos = row >> 4, b = row & 15;
  int oh = pos / 3, ow = pos % 3;
  for(int k = threadIdx.x; k < 4608; k += 256){
    int cin = k / 9, q = k - cin * 9;
    int kh = q / 3, kw = q - kh * 3;
    int ih = oh + kh - 1, iw = ow + kw - 1;
    ih = ih < 0 ? -ih : (ih > 2 ? 4 - ih : ih);
    iw = iw < 0 ? -iw : (iw > 2 ? 4 - iw : iw);
    float v = w[((size_t)(b * 512 + cin) * 3 + ih) * 3 + iw];
    A[(size_t)row * 4608 + k] = f2b(v);
  }
}

// ------------- pw[b][4096] and bias[b][512] -------------
__global__ __launch_bounds__(256) void k_pwbias(const float* __restrict__ pooled,
    const float* __restrict__ kp_pw, const float* __restrict__ kp_pb,
    const float* __restrict__ kp_bw, const float* __restrict__ kp_bb,
    float* __restrict__ pw, float* __restrict__ bias){
  int wid = (blockIdx.x * 256 + threadIdx.x) >> 6;   // 4608 waves
  int lane = threadIdx.x & 63;
  const float* row;
  float bv;
  if(wid < 4096){ row = kp_pw + (size_t)wid * 512; bv = kp_pb[wid]; }
  else          { row = kp_bw + (size_t)(wid - 4096) * 512; bv = kp_bb[wid - 4096]; }
  float r[8];
  #pragma unroll
  for(int i = 0; i < 8; i++) r[i] = row[lane + 64 * i];
  for(int b = 0; b < 16; b++){
    float s = 0.f;
    #pragma unroll
    for(int i = 0; i < 8; i++) s += r[i] * pooled[b * 512 + lane + 64 * i];
    #pragma unroll
    for(int o = 32; o >= 1; o >>= 1) s += __shfl_xor(s, o, 64);
    if(lane == 0){
      if(wid < 4096) pw[b * 4096 + wid] = s + bv;
      else           bias[b * 512 + (wid - 4096)] = s + bv;
    }
  }
}

// ------------- KernelPredictor spatial GEMM, 12-way split-K -------------
__global__ __launch_bounds__(256) void k_gemmB(const unsigned short* __restrict__ Aim,
    const float* __restrict__ kp_sw, float* __restrict__ part){
  __shared__ unsigned short Al[144 * 72];
  __shared__ unsigned short Bl[64 * 72];
  int tid = threadIdx.x;
  int lane = tid & 63, wv = tid >> 6;
  int n0 = blockIdx.x * 64;
  int kz = blockIdx.y;
  f32x4 acc[9] = {};
  for(int ks = kz * 6; ks < kz * 6 + 6; ks++){
    int kb = ks * 64;
    for(int c = tid; c < 1152; c += 256){
      int m = c >> 3, kc = c & 7;
      *(int4*)&Al[m * 72 + kc * 8] = *(const int4*)(Aim + (size_t)m * 4608 + kb + kc * 8);
    }
    for(int c = tid; c < 512; c += 256){
      int n = c >> 3, kc = c & 7;
      const float4* src = (const float4*)(kp_sw + (size_t)(n0 + n) * 4608 + kb + kc * 8);
      float4 v0 = src[0], v1 = src[1];
      unsigned short tmp[8];
      tmp[0]=f2b(v0.x); tmp[1]=f2b(v0.y); tmp[2]=f2b(v0.z); tmp[3]=f2b(v0.w);
      tmp[4]=f2b(v1.x); tmp[5]=f2b(v1.y); tmp[6]=f2b(v1.z); tmp[7]=f2b(v1.w);
      *(int4*)&Bl[n * 72 + kc * 8] = *(int4*)tmp;
    }
    __syncthreads();
    int r16 = lane & 15, khalf = lane >> 4;
    #pragma unroll
    for(int kk = 0; kk < 2; kk++){
      int ko = kk * 32 + khalf * 8;
      short8 bf = *(const short8*)&Bl[(wv * 16 + r16) * 72 + ko];
      #pragma unroll
      for(int mf = 0; mf < 9; mf++){
        short8 af = *(const short8*)&Al[(mf * 16 + r16) * 72 + ko];
        acc[mf] = __builtin_amdgcn_mfma_f32_16x16x32_bf16(af, bf, acc[mf], 0, 0, 0);
      }
    }
    __syncthreads();
  }
  int r16 = lane & 15, rgrp = lane >> 4;
  int n = n0 + wv * 16 + r16;
  #pragma unroll
  for(int mf = 0; mf < 9; mf++){
    #pragma unroll
    for(int r = 0; r < 4; r++){
      int m = mf * 16 + rgrp * 4 + r;
      part[((size_t)kz * 144 + m) * 4096 + n] = acc[mf][r];
    }
  }
}

// ------------- split-K reduce + bias + transpose into dw[b][n][9] -------------
__global__ __launch_bounds__(256) void k_red(const float* __restrict__ part,
    const float* __restrict__ kp_sb, float* __restrict__ dw){
  int i = blockIdx.x * 256 + threadIdx.x;   // 589824
  int m = i >> 12, n = i & 4095;
  float s = kp_sb[n];
  #pragma unroll
  for(int kz = 0; kz < 12; kz++) s += part[((size_t)kz * 144 + m) * 4096 + n];
  int q = m >> 4, b = m & 15;
  dw[((size_t)b * 4096 + n) * 9 + q] = s;
}

// ------ AdaConv fused (blocks 0..1023) + y1p pad-ring zero (blocks 1024..1551) ------
// ring must run AFTER k_red (y1p aliases split-K partials) — satisfied by stream order.
__global__ __launch_bounds__(256) void k_ada(const float* __restrict__ x,
    const float* __restrict__ dwb, const float* __restrict__ pwb,
    const float* __restrict__ biasb, unsigned short* __restrict__ y0p,
    unsigned short* __restrict__ y1p){
  int bg = blockIdx.x;
  if(bg >= 1024){
    int i = (bg - 1024) * 256 + threadIdx.x;   // 528*256 = 135168 = 16*132*64
    int b = i / 8448, rem = i - b * 8448;
    int e = rem >> 6, ch8 = rem & 63;
    int hh, ww;
    if(e < 34){ hh = 0; ww = e; }
    else if(e < 68){ hh = 33; ww = e - 34; }
    else if(e < 100){ hh = e - 68 + 1; ww = 0; }
    else { hh = e - 100 + 1; ww = 33; }
    int4 z = {0, 0, 0, 0};
    *(int4*)&y1p[((size_t)(b * 34 + hh) * 34 + ww) * 512 + ch8 * 8] = z;
    return;
  }
  __shared__ float xn[8][1156];
  __shared__ float dwl[576];
  __shared__ float pwl[64];
  __shared__ float bl[8];
  __shared__ float red0[4][8], red1[4][8];
  __shared__ float ms[8], rs[8];
  int b = bg >> 6, g = bg & 63;
  int tid = threadIdx.x;
  int lane = tid & 63, wv = tid >> 6;
  for(int i = tid; i < 576; i += 256) dwl[i] = dwb[((size_t)b * 4096 + g * 64) * 9 + i];
  if(tid < 64) pwl[tid] = pwb[b * 4096 + g * 64 + tid];
  if(tid < 8)  bl[tid]  = biasb[b * 512 + g * 8 + tid];
  // zero y0p pad ring for this (b,g) slice
  if(tid < 132){
    int e = tid, hh, ww;
    if(e < 34){ hh = 0; ww = e; }
    else if(e < 68){ hh = 33; ww = e - 34; }
    else if(e < 100){ hh = e - 68 + 1; ww = 0; }
    else { hh = e - 100 + 1; ww = 33; }
    int4 z = {0, 0, 0, 0};
    *(int4*)&y0p[((size_t)(b * 34 + hh) * 34 + ww) * 512 + g * 8] = z;
  }
  // load interior (float4) + per-channel partial sums
  const float* xb = x + ((size_t)(b * 512 + g * 8)) * 1024;
  int h4 = tid >> 3, w4 = (tid & 7) * 4;
  float s[8], s2[8];
  #pragma unroll
  for(int ci = 0; ci < 8; ci++){
    float4 v = *(const float4*)(xb + ci * 1024 + tid * 4);
    float* dst = &xn[ci][(h4 + 1) * 34 + w4 + 1];
    dst[0] = v.x; dst[1] = v.y; dst[2] = v.z; dst[3] = v.w;
    s[ci]  = v.x + v.y + v.z + v.w;
    s2[ci] = v.x * v.x + v.y * v.y + v.z * v.z + v.w * v.w;
  }
  #pragma unroll
  for(int ci = 0; ci < 8; ci++){
    #pragma unroll
    for(int o = 32; o >= 1; o >>= 1){
      s[ci]  += __shfl_xor(s[ci],  o, 64);
      s2[ci] += __shfl_xor(s2[ci], o, 64);
    }
  }
  if(lane == 0){
    #pragma unroll
    for(int ci = 0; ci < 8; ci++){ red0[wv][ci] = s[ci]; red1[wv][ci] = s2[ci]; }
  }
  __syncthreads();
  if(tid < 8){
    float S  = red0[0][tid] + red0[1][tid] + red0[2][tid] + red0[3][tid];
    float S2 = red1[0][tid] + red1[1][tid] + red1[2][tid] + red1[3][tid];
    float m = S * (1.f / 1024.f);
    ms[tid] = m;
    rs[tid] = rsqrtf(S2 * (1.f / 1024.f) - m * m + 1e-5f);
  }
  __syncthreads();
  // normalize interior in place
  #pragma unroll
  for(int ci = 0; ci < 8; ci++){
    float m = ms[ci], r = rs[ci];
    float* p = &xn[ci][(h4 + 1) * 34 + w4 + 1];
    #pragma unroll
    for(int j = 0; j < 4; j++) p[j] = (p[j] - m) * r;
  }
  __syncthreads();
  // fill reflect halo from normalized interior
  for(int idx = tid; idx < 1056; idx += 256){
    int ci = idx / 132, e = idx - ci * 132;
    int hh, ww;
    if(e < 34){ hh = 0; ww = e; }
    else if(e < 68){ hh = 33; ww = e - 34; }
    else if(e < 100){ hh = e - 68 + 1; ww = 0; }
    else { hh = e - 100 + 1; ww = 33; }
    int h = hh - 1, w2 = ww - 1;
    h  = h  < 0 ? 1 : (h  > 31 ? 30 : h);
    w2 = w2 < 0 ? 1 : (w2 > 31 ? 30 : w2);
    xn[ci][hh * 34 + ww] = xn[ci][(h + 1) * 34 + (w2 + 1)];
  }
  __syncthreads();
  // grouped spatial conv + pointwise + bias
  float acc[4][8] = {};
  #pragma unroll
  for(int i = 0; i < 8; i++){
    #pragma unroll
    for(int q = 0; q < 9; q++){
      int kh = q / 3, kw = q - kh * 3;
      float dvs[8];
      #pragma unroll
      for(int o = 0; o < 8; o++) dvs[o] = dwl[(o * 8 + i) * 9 + q];
      #pragma unroll
      for(int pp = 0; pp < 4; pp++){
        int p = pp * 256 + tid; int h = p >> 5, w = p & 31;
        float v = xn[i][(h + kh) * 34 + (w + kw)];
        #pragma unroll
        for(int o = 0; o < 8; o++) acc[pp][o] += v * dvs[o];
      }
    }
  }
  #pragma unroll
  for(int pp = 0; pp < 4; pp++){
    int p = pp * 256 + tid; int h = p >> 5, w = p & 31;
    unsigned short pack[8];
    #pragma unroll
    for(int o = 0; o < 8; o++){
      float sv = bl[o];
      #pragma unroll
      for(int i2 = 0; i2 < 8; i2++) sv += pwl[o * 8 + i2] * acc[pp][i2];
      pack[o] = f2b(sv);
    }
    *(int4*)&y0p[((size_t)(b * 34 + h + 1) * 34 + (w + 1)) * 512 + g * 8] = *(int4*)pack;
  }
}

// ------------- decoder 3x3 conv: implicit GEMM, 2-buffer counted-vmcnt two-barrier pipeline -------------
// 512 threads = 8 waves (2M x 4N), per-wave 64x32 out. LDS 2 x ([128][64] A + [128][64] B) = 64 KB
// -> 2 blocks/CU (16 waves/CU). T2 swizzle via pre-swizzled source + swizzled ds_read.
// Schedule per K-step t: COMPUTE(buf) ; barrier ; STAGE(t+2 -> buf) ; vmcnt(4) ; barrier  (T4: never drain to 0)
template<int NCOUT, int OUT_PADDED>
__global__ __launch_bounds__(512) void k_conv(const unsigned short* __restrict__ inp,
    const unsigned short* __restrict__ wt, const float* __restrict__ bias,
    unsigned short* __restrict__ outp){
  __shared__ unsigned short Al[2][128 * 64];
  __shared__ unsigned short Bl[2][128 * 64];
  int tid = threadIdx.x;
  int mt = blockIdx.x;                 // 128 m-tiles
  int n0 = blockIdx.y * 128;
  int b = mt >> 3, h0 = (mt & 7) * 4;
  int lane = tid & 63, wv = tid >> 6;
  int wm = (wv >> 2) * 64, wn = (wv & 3) * 32;
  f32x4 acc[4][2] = {};
  const size_t bbase = (size_t)b * 34 * 34 * 512;

  // staging constants: chunks c = tid + 512*j, row = c>>3, slot = c&7
  int kc = tid & 7;
  int m0 = tid >> 3, m1 = (tid + 512) >> 3;
  int colA0 = kc ^ (m0 & 7), colA1 = kc ^ (m1 & 7);
  int mh0 = m0 >> 5, mw0 = m0 & 31;
  int mh1 = m1 >> 5, mw1 = m1 & 31;
  int ldsO0 = (tid & ~63) * 8;
  int ldsO1 = ldsO0 + 512 * 8;
  const unsigned short* a0base = inp + bbase + colA0 * 8;
  const unsigned short* a1base = inp + bbase + colA1 * 8;
  const unsigned short* b0base = wt + (size_t)(n0 + m0) * 4608 + colA0 * 8;
  const unsigned short* b1base = wt + (size_t)(n0 + m1) * 4608 + colA1 * 8;
  int r16 = lane & 15, khalf = lane >> 4;

#define STAGE(T, BUF) { \
    int q_ = (T) >> 3, cb_ = ((T) & 7) * 64; \
    int kh_ = q_ / 3, kw_ = q_ - kh_ * 3; \
    gll16(a0base + (size_t)((h0 + mh0 + kh_) * 34 + mw0 + kw_) * 512 + cb_, &Al[BUF][ldsO0]); \
    gll16(a1base + (size_t)((h0 + mh1 + kh_) * 34 + mw1 + kw_) * 512 + cb_, &Al[BUF][ldsO1]); \
    gll16(b0base + (size_t)q_ * 512 + cb_, &Bl[BUF][ldsO0]); \
    gll16(b1base + (size_t)q_ * 512 + cb_, &Bl[BUF][ldsO1]); }

#define COMPUTE(BUF) { \
    const unsigned short* Ab = Al[BUF]; const unsigned short* Bb = Bl[BUF]; \
    { int sc8 = (khalf ^ (r16 & 7)) * 8; \
      short8 af[4], bf[2]; \
      _Pragma("unroll") for(int i = 0; i < 4; i++) af[i] = *(const short8*)&Ab[(wm + i * 16 + r16) * 64 + sc8]; \
      _Pragma("unroll") for(int i = 0; i < 2; i++) bf[i] = *(const short8*)&Bb[(wn + i * 16 + r16) * 64 + sc8]; \
      __builtin_amdgcn_s_setprio(1); \
      _Pragma("unroll") for(int mi = 0; mi < 4; mi++) \
        _Pragma("unroll") for(int ni = 0; ni < 2; ni++) \
          acc[mi][ni] = __builtin_amdgcn_mfma_f32_16x16x32_bf16(af[mi], bf[ni], acc[mi][ni], 0, 0, 0); \
      __builtin_amdgcn_s_setprio(0); } \
    { int sc8 = ((4 + khalf) ^ (r16 & 7)) * 8; \
      short8 af[4], bf[2]; \
      _Pragma("unroll") for(int i = 0; i < 4; i++) af[i] = *(const short8*)&Ab[(wm + i * 16 + r16) * 64 + sc8]; \
      _Pragma("unroll") for(int i = 0; i < 2; i++) bf[i] = *(const short8*)&Bb[(wn + i * 16 + r16) * 64 + sc8]; \
      __builtin_amdgcn_s_setprio(1); \
      _Pragma("unroll") for(int mi = 0; mi < 4; mi++) \
        _Pragma("unroll") for(int ni = 0; ni < 2; ni++) \
          acc[mi][ni] = __builtin_amdgcn_mfma_f32_16x16x32_bf16(af[mi], bf[ni], acc[mi][ni], 0, 0, 0); \
      __builtin_amdgcn_s_setprio(0); } }

  // prologue: buffers 0,1 in flight; wait for buf0 only (stage(1) stays in flight)
  STAGE(0, 0)
  STAGE(1, 1)
  vm_wait4(); __builtin_amdgcn_s_barrier();
  // main loop: steps 0..69, stage(t+2) issued after first barrier, drained next step by vmcnt(4)
  for(int t = 0; t < 70; t += 2){
    COMPUTE(0)
    __builtin_amdgcn_s_barrier();
    STAGE(t + 2, 0)
    vm_wait4(); __builtin_amdgcn_s_barrier();
    COMPUTE(1)
    __builtin_amdgcn_s_barrier();
    STAGE(t + 3, 1)
    vm_wait4(); __builtin_amdgcn_s_barrier();
  }
  // tail: steps 70, 71 (no more stages; stage(71) still <=4 outstanding)
  COMPUTE(0)
  vm_wait0(); __builtin_amdgcn_s_barrier();
  COMPUTE(1)
#undef STAGE
#undef COMPUTE

  int rgrp = lane >> 4;
  #pragma unroll
  for(int ni = 0; ni < 2; ni++){
    int n = n0 + wn + ni * 16 + r16;
    float bv = bias[n];
    #pragma unroll
    for(int mi = 0; mi < 4; mi++){
      #pragma unroll
      for(int r = 0; r < 4; r++){
        int row = wm + mi * 16 + rgrp * 4 + r;
        int h = h0 + (row >> 5), w = row & 31;
        float v = acc[mi][ni][r] + bv;
        v = v > 0.f ? v : 0.f;
        size_t oidx;
        if(OUT_PADDED) oidx = ((size_t)(b * 34 + h + 1) * 34 + (w + 1)) * 512 + n;
        else           oidx = ((size_t)(b * 32 + h) * 32 + w) * NCOUT + n;
        outp[oidx] = f2b(v);
      }
    }
  }
}

// ------------- nearest 2x upsample + NHWC bf16 -> NCHW fp32 -------------
__global__ __launch_bounds__(256) void k_up(const unsigned short* __restrict__ y2,
                                            float* __restrict__ out){
  __shared__ unsigned short ld[32 * 258];
  int bh = blockIdx.x; int b = bh >> 5, h = bh & 31;
  int tid = threadIdx.x;
  const unsigned short* src = y2 + ((size_t)b * 1024 + h * 32) * 256;
  for(int c = tid; c < 1024; c += 256){
    int w = c >> 5, kc = c & 31;
    *(int4*)&ld[w * 258 + kc * 8] = *(const int4*)&src[w * 256 + kc * 8];
  }
  __syncthreads();
  int q = tid & 3, co0 = tid >> 2;
  for(int cc = 0; cc < 4; cc++){
    int co = cc * 64 + co0;
    size_t obase = ((size_t)(b * 256 + co) * 64 + h * 2) * 64 + q * 16;
    #pragma unroll
    for(int i = 0; i < 4; i++){
      float a  = b2f(ld[(q * 8 + i * 2) * 258 + co]);
      float b2 = b2f(ld[(q * 8 + i * 2 + 1) * 258 + co]);
      float4 v = make_float4(a, a, b2, b2);
      *(float4*)&out[obase + i * 4]      = v;
      *(float4*)&out[obase + 64 + i * 4] = v;
    }
  }
}

extern "C" void kernel_launch(void* const* d_in, const int* in_sizes, int n_in,
                              void* d_out, int out_size, void* d_ws, size_t ws_size,
                              hipStream_t stream){
  (void)in_sizes; (void)n_in; (void)out_size; (void)ws_size;
  const float* x      = (const float*)d_in[0];
  const float* w      = (const float*)d_in[1];
  const float* kp_sw  = (const float*)d_in[2];
  const float* kp_sb  = (const float*)d_in[3];
  const float* kp_pw  = (const float*)d_in[4];
  const float* kp_pb  = (const float*)d_in[5];
  const float* kp_bw  = (const float*)d_in[6];
  const float* kp_bb  = (const float*)d_in[7];
  const float* dec_w1 = (const float*)d_in[8];
  const float* dec_b1 = (const float*)d_in[9];
  const float* dec_w2 = (const float*)d_in[10];
  const float* dec_b2 = (const float*)d_in[11];
  char* ws = (char*)d_ws;
  float*          pooled = (float*)(ws);                        // 32 KB
  float*          pw     = (float*)(ws + 32768);                // 256 KB
  float*          bias   = (float*)(ws + 294912);               // 32 KB
  unsigned short* Aim    = (unsigned short*)(ws + 393216);      // 1.33 MB
  float*          dw     = (float*)(ws + 1720320);              // 2.36 MB
  unsigned short* w1t    = (unsigned short*)(ws + 4079616);     // 4.72 MB
  unsigned short* w2t    = (unsigned short*)(ws + 8798208);     // 2.36 MB
  unsigned short* y0p    = (unsigned short*)(ws + 11157504);    // 18.94 MB
  unsigned short* y1p    = (unsigned short*)(ws + 30097408);    // 18.94 MB
  unsigned short* y2     = (unsigned short*)(ws + 49037312);    // 8.39 MB
  // split-K partials (12 x 144 x 4096 fp32 = 28.3 MB) alias y0p + y1p head;
  // consumed by k_red BEFORE k_ada (ring) / k_conv overwrite that region.
  float*          part   = (float*)(ws + 11157504);

  k_prepwt<<<944,  256, 0, stream>>>(w, Aim, pooled, dec_w1, dec_w2, w1t, w2t);
  k_pwbias<<<1152, 256, 0, stream>>>(pooled, kp_pw, kp_pb, kp_bw, kp_bb, pw, bias);
  k_gemmB <<<dim3(64, 12), 256, 0, stream>>>(Aim, kp_sw, part);
  k_red   <<<2304, 256, 0, stream>>>(part, kp_sb, dw);
  k_ada   <<<1552, 256, 0, stream>>>(x, dw, pw, bias, y0p, y1p);
  k_conv<512, 1><<<dim3(128, 4), 512, 0, stream>>>(y0p, w1t, dec_b1, y1p);
  k_conv<256, 0><<<dim3(128, 2), 512, 0, stream>>>(y1p, w2t, dec_b2, y2);
  k_up    <<<512,  256, 0, stream>>>(y2, (float*)d_out);
}